// Round 14
// baseline (338.259 us; speedup 1.0000x reference)
//
#include <hip/hip_runtime.h>
#include <hip/hip_bf16.h>

typedef __attribute__((ext_vector_type(8))) short s8v;   // 8 x bf16 (bit pattern)
typedef __attribute__((ext_vector_type(4))) float f4v;   // MFMA accumulator

#define DEV static __device__ __forceinline__

__device__ const float SCQ = 0.18033688011112042f;   // (1/8) * log2(e)

DEV unsigned short f2bf(float f) {
    unsigned int u = __builtin_bit_cast(unsigned int, f);
    unsigned int r = u + 0x7FFFu + ((u >> 16) & 1u);
    return (unsigned short)(r >> 16);
}

DEV f4v fzero() { f4v v = {0.f, 0.f, 0.f, 0.f}; return v; }

// fast GELU (tanh form): x * sigmoid(1.5957691*(x + 0.044715 x^3))
DEV float fgelu(float x) {
    float z = x * (1.5957691f + 0.07135482f * x * x);
    float s = __builtin_amdgcn_rcpf(1.0f + __expf(-z));
    return x * s;
}

DEV void gload16(const void* g, void* l) {
    __builtin_amdgcn_global_load_lds(
        (const __attribute__((address_space(1))) unsigned int*)g,
        (__attribute__((address_space(3))) unsigned int*)l, 16, 0, 0);
}

// ---------------- fused transpose of 8 (1024,1024) f32 weights -> bf16 -----
struct P8 { const float* p[8]; };
__global__ __launch_bounds__(256) void k_transpose8(
        P8 ws8, unsigned short* __restrict__ base) {
    __shared__ float tile[32][33];
    int z = blockIdx.z;
    const float* W = ws8.p[z];
    unsigned short* Wt = base + (size_t)z * 1024 * 1024;
    int tx = threadIdx.x & 31, ty = threadIdx.x >> 5;
    int n0 = blockIdx.x * 32, k0 = blockIdx.y * 32;
#pragma unroll
    for (int r = 0; r < 32; r += 8)
        tile[ty + r][tx] = W[(size_t)(k0 + ty + r) * 1024 + n0 + tx];
    __syncthreads();
#pragma unroll
    for (int r = 0; r < 32; r += 8)
        Wt[(size_t)(n0 + ty + r) * 1024 + k0 + tx] = f2bf(tile[tx][ty + r]);
}

// ---------------- weight transpose f32 (K,N) -> bf16 (N,K) ----------------
__global__ __launch_bounds__(256) void k_transpose_bf16(
        const float* __restrict__ W, unsigned short* __restrict__ Wt, int K, int N) {
    __shared__ float tile[32][33];
    int tx = threadIdx.x & 31, ty = threadIdx.x >> 5;
    int n0 = blockIdx.x * 32, k0 = blockIdx.y * 32;
#pragma unroll
    for (int r = 0; r < 32; r += 8)
        tile[ty + r][tx] = W[(size_t)(k0 + ty + r) * N + n0 + tx];
    __syncthreads();
#pragma unroll
    for (int r = 0; r < 32; r += 8)
        Wt[(size_t)(n0 + ty + r) * K + k0 + tx] = f2bf(tile[tx][ty + r]);
}

// ---------------- elementwise f32 -> bf16 ----------------
__global__ __launch_bounds__(256) void k_f32_to_bf16(
        const float* __restrict__ in, unsigned short* __restrict__ out, int n) {
    int i = (blockIdx.x * 256 + threadIdx.x) * 8;
    if (i >= n) return;
    float4 a = *(const float4*)(in + i);
    float4 b = *(const float4*)(in + i + 4);
    uint4 o;
    o.x = f2bf(a.x) | ((unsigned)f2bf(a.y) << 16);
    o.y = f2bf(a.z) | ((unsigned)f2bf(a.w) << 16);
    o.z = f2bf(b.x) | ((unsigned)f2bf(b.y) << 16);
    o.w = f2bf(b.z) | ((unsigned)f2bf(b.w) << 16);
    *(uint4*)(out + i) = o;
}

// ---------------- bias concat: [sa_bq|sa_bk|sa_bv|ca_bk|ca_bv] ----------------
__global__ __launch_bounds__(256) void k_bias_cat(
        const float* q, const float* k, const float* v,
        const float* k2, const float* v2, float* out) {
    int i = blockIdx.x * 256 + threadIdx.x;  // 5120 total
    float val;
    if (i < 1024) val = q[i];
    else if (i < 2048) val = k[i - 1024];
    else if (i < 3072) val = v[i - 2048];
    else if (i < 4096) val = k2[i - 3072];
    else val = v2[i - 4096];
    out[i] = val;
}

// ---------------- LayerNorm f32 -> bf16 (C=1024) ----------------
__global__ __launch_bounds__(256) void k_layernorm(
        const float* __restrict__ x, const float* __restrict__ g,
        const float* __restrict__ b, unsigned short* __restrict__ out) {
    int row = blockIdx.x;
    int t = threadIdx.x;
    const float* xr = x + (size_t)row * 1024;
    float4 v = *(const float4*)(xr + t * 4);
    float s = v.x + v.y + v.z + v.w;
    float ss = v.x * v.x + v.y * v.y + v.z * v.z + v.w * v.w;
#pragma unroll
    for (int m = 1; m < 64; m <<= 1) { s += __shfl_xor(s, m); ss += __shfl_xor(ss, m); }
    __shared__ float red[16];
    int w = t >> 6;
    if ((t & 63) == 0) { red[w] = s; red[8 + w] = ss; }
    __syncthreads();
    s = red[0] + red[1] + red[2] + red[3];
    ss = red[8] + red[9] + red[10] + red[11];
    float mu = s * (1.f / 1024.f);
    float rstd = rsqrtf(ss * (1.f / 1024.f) - mu * mu + 1e-5f);
    float4 gv = *(const float4*)(g + t * 4);
    float4 bv = *(const float4*)(b + t * 4);
    float y0 = (v.x - mu) * rstd * gv.x + bv.x;
    float y1 = (v.y - mu) * rstd * gv.y + bv.y;
    float y2 = (v.z - mu) * rstd * gv.z + bv.z;
    float y3 = (v.w - mu) * rstd * gv.w + bv.w;
    uint2 o;
    o.x = f2bf(y0) | ((unsigned)f2bf(y1) << 16);
    o.y = f2bf(y2) | ((unsigned)f2bf(y3) << 16);
    *(uint2*)(out + (size_t)row * 1024 + t * 4) = o;
}

// ============ GEMM v1: 128/64 x 128 tile ===================================
// 3-buffer counted-vmcnt pipeline, chunk-XOR LDS swizzle w/ pre-swizzled
// source, XCD swizzle, setprio MFMA cluster, LDS-bounce epilogue.
// EPI 0: bf16+bias (cols<scaleN get x SCQ)  1: bf16 fgelu  2: f32 res+acc+bias
template <int EPI, int BM>
__global__ __launch_bounds__(256) void k_gemm(
        const unsigned short* __restrict__ A, const unsigned short* __restrict__ Bt,
        const float* __restrict__ bias, const float* __restrict__ res,
        void* __restrict__ outv, int M, int N, int K, int scaleN) {
    constexpr int WI = (BM == 128) ? 4 : 2;       // 16-row frags per wave
    constexpr int ABUF = BM * 64;                 // bytes per A buffer
    constexpr int BUFSZ = ABUF + 8192;            // A + B per K-tile
    __shared__ __align__(16) char smem[3 * BUFSZ];
    int nbx = N >> 7;
    int bid = blockIdx.x;
    int cpx = gridDim.x >> 3;          // all grids are %8 == 0
    int swz = (bid & 7) * cpx + (bid >> 3);
    int bx = swz % nbx, by = swz / nbx;
    int m0 = by * BM, n0 = bx << 7;
    int tid = threadIdx.x, w = tid >> 6, l = tid & 63;
    int wr = w >> 1, wc = w & 1;
    int lq = l >> 4, lc = l & 15;
    f4v acc[WI][4];
#pragma unroll
    for (int i = 0; i < WI; ++i)
#pragma unroll
        for (int j = 0; j < 4; ++j) acc[i][j] = fzero();
    const unsigned short* Ab = A + (size_t)m0 * K;
    const unsigned short* Bb = Bt + (size_t)n0 * K;
    int arow = w * 16 + (l >> 2);                       // 0..63
    int ach = (((l & 3) ^ ((arow >> 1) & 3)) << 3);     // pre-swizzled k-chunk

    auto STAGE = [&](int t) {
        int kt = t << 5;
        char* buf = smem + (t % 3) * BUFSZ;
        gload16(Ab + (size_t)arow * K + kt + ach, buf + w * 1024);
        if constexpr (BM == 128)
            gload16(Ab + (size_t)(64 + arow) * K + kt + ach, buf + 4096 + w * 1024);
        gload16(Bb + (size_t)arow * K + kt + ach, buf + ABUF + w * 1024);
        gload16(Bb + (size_t)(64 + arow) * K + kt + ach, buf + ABUF + 4096 + w * 1024);
    };
    int cs = ((lq ^ ((lc >> 1) & 3)) << 4);             // read-side swizzle
    auto COMPUTE = [&](int t) {
        const char* buf = smem + (t % 3) * BUFSZ;
        s8v af[WI], bfr[4];
#pragma unroll
        for (int i = 0; i < WI; ++i)
            af[i] = *(const s8v*)(buf + (wr * (BM / 2) + i * 16 + lc) * 64 + cs);
#pragma unroll
        for (int j = 0; j < 4; ++j)
            bfr[j] = *(const s8v*)(buf + ABUF + (wc * 64 + j * 16 + lc) * 64 + cs);
        __builtin_amdgcn_s_setprio(1);
#pragma unroll
        for (int i = 0; i < WI; ++i)
#pragma unroll
            for (int j = 0; j < 4; ++j)
                acc[i][j] = __builtin_amdgcn_mfma_f32_16x16x32_bf16(af[i], bfr[j], acc[i][j], 0, 0, 0);
        __builtin_amdgcn_s_setprio(0);
    };

    int NT = K >> 5;
    STAGE(0); STAGE(1);
    if constexpr (BM == 128) asm volatile("s_waitcnt vmcnt(4)" ::: "memory");
    else                     asm volatile("s_waitcnt vmcnt(3)" ::: "memory");
    __builtin_amdgcn_s_barrier();
    for (int t = 0; t < NT; ++t) {
        if (t + 2 < NT) STAGE(t + 2);
        COMPUTE(t);
        if (t + 2 < NT) {
            if constexpr (BM == 128) asm volatile("s_waitcnt vmcnt(4)" ::: "memory");
            else                     asm volatile("s_waitcnt vmcnt(3)" ::: "memory");
        } else if (t + 1 < NT) {
            asm volatile("s_waitcnt vmcnt(0)" ::: "memory");
        }
        __builtin_amdgcn_s_barrier();
    }

    // ---- epilogue: LDS bounce -> coalesced 8/16B stores ----
    float* esc = (float*)smem + w * 1088;   // per-wave 16 rows x 68 words
#pragma unroll
    for (int i = 0; i < WI; ++i) {
#pragma unroll
        for (int j = 0; j < 4; ++j)
#pragma unroll
            for (int r = 0; r < 4; ++r)
                esc[(lq * 4 + r) * 68 + j * 16 + lc] = acc[i][j][r];
#pragma unroll
        for (int p = 0; p < 4; ++p) {
            int rr = p * 4 + lq;
            float4 v = *(const float4*)(esc + rr * 68 + lc * 4);
            int row = m0 + wr * (BM / 2) + i * 16 + rr;
            int col = n0 + wc * 64 + lc * 4;
            float4 bv = *(const float4*)(bias + col);
            v.x += bv.x; v.y += bv.y; v.z += bv.z; v.w += bv.w;
            size_t idx = (size_t)row * N + col;
            if (EPI == 0) {
                float scl = (col < scaleN) ? SCQ : 1.0f;
                ushort4 o;
                o.x = f2bf(v.x * scl); o.y = f2bf(v.y * scl);
                o.z = f2bf(v.z * scl); o.w = f2bf(v.w * scl);
                *(ushort4*)((unsigned short*)outv + idx) = o;
            } else if (EPI == 1) {
                ushort4 o;
                o.x = f2bf(fgelu(v.x)); o.y = f2bf(fgelu(v.y));
                o.z = f2bf(fgelu(v.z)); o.w = f2bf(fgelu(v.w));
                *(ushort4*)((unsigned short*)outv + idx) = o;
            } else {
                float4 rv = *(const float4*)(res + idx);
                v.x += rv.x; v.y += rv.y; v.z += rv.z; v.w += rv.w;
                *(float4*)((float*)outv + idx) = v;
            }
        }
    }
}

// ============ GEMM v2: 128x256 tile, wave = 64x128 (acc 4x8) ===============
// 2-phase per-tile interleave, 3-buffer counted vmcnt(6), setprio clusters.
// EPI 0: bf16+bias (cols<scaleN get x SCQ)   1: bf16 fgelu
template <int EPI>
__global__ __launch_bounds__(256, 2) void k_gemm2(
        const unsigned short* __restrict__ A, const unsigned short* __restrict__ Bt,
        const float* __restrict__ bias, void* __restrict__ outv,
        int M, int N, int K, int scaleN) {
    constexpr int BUFSZ = 8192 + 16384;   // A(128x64B) + B(256x64B)
    __shared__ __align__(16) char smem[3 * BUFSZ];
    int nbx = N >> 8;
    int bid = blockIdx.x;
    int cpx = gridDim.x >> 3;             // grids are %8 == 0
    int swz = (bid & 7) * cpx + (bid >> 3);
    int bx = swz % nbx, by = swz / nbx;
    int m0 = by << 7, n0 = bx << 8;
    int tid = threadIdx.x, w = tid >> 6, l = tid & 63;
    int wr = w >> 1, wc = w & 1;
    int lq = l >> 4, lc = l & 15;
    f4v acc[4][8];
#pragma unroll
    for (int i = 0; i < 4; ++i)
#pragma unroll
        for (int j = 0; j < 8; ++j) acc[i][j] = fzero();
    const unsigned short* Ab = A + (size_t)m0 * K;
    const unsigned short* Bb = Bt + (size_t)n0 * K;
    int arow = w * 16 + (l >> 2);                       // 0..63
    int ach = (((l & 3) ^ ((arow >> 1) & 3)) << 3);     // pre-swizzled k-chunk

    auto STAGE_P0 = [&](int t) {       // A both halves + B halves 0,1
        int kt = t << 5;
        char* buf = smem + (t % 3) * BUFSZ;
        gload16(Ab + (size_t)arow * K + kt + ach, buf + w * 1024);
        gload16(Ab + (size_t)(64 + arow) * K + kt + ach, buf + 4096 + w * 1024);
        gload16(Bb + (size_t)arow * K + kt + ach, buf + 8192 + w * 1024);
        gload16(Bb + (size_t)(64 + arow) * K + kt + ach, buf + 8192 + 4096 + w * 1024);
    };
    auto STAGE_P1 = [&](int t) {       // B halves 2,3
        int kt = t << 5;
        char* buf = smem + (t % 3) * BUFSZ;
        gload16(Bb + (size_t)(128 + arow) * K + kt + ach, buf + 8192 + 8192 + w * 1024);
        gload16(Bb + (size_t)(192 + arow) * K + kt + ach, buf + 8192 + 12288 + w * 1024);
    };
    int cs = ((lq ^ ((lc >> 1) & 3)) << 4);             // read-side swizzle

    int NT = K >> 5;
    STAGE_P0(0); STAGE_P1(0); STAGE_P0(1); STAGE_P1(1);
    asm volatile("s_waitcnt vmcnt(6)" ::: "memory");
    __builtin_amdgcn_s_barrier();
    for (int t = 0; t < NT; ++t) {
        const char* buf = smem + (t % 3) * BUFSZ;
        bool pf = (t + 2 < NT);
        // ---- phase A: A frags + B cols 0..3; stage 4 of 6 ----
        s8v af[4], bfr[8];
#pragma unroll
        for (int i = 0; i < 4; ++i)
            af[i] = *(const s8v*)(buf + (wr * 64 + i * 16 + lc) * 64 + cs);
#pragma unroll
        for (int j = 0; j < 4; ++j)
            bfr[j] = *(const s8v*)(buf + 8192 + (wc * 128 + j * 16 + lc) * 64 + cs);
        if (pf) STAGE_P0(t + 2);
        asm volatile("s_waitcnt lgkmcnt(0)" ::: "memory");
        __builtin_amdgcn_sched_barrier(0);
        __builtin_amdgcn_s_setprio(1);
#pragma unroll
        for (int i = 0; i < 4; ++i)
#pragma unroll
            for (int j = 0; j < 4; ++j)
                acc[i][j] = __builtin_amdgcn_mfma_f32_16x16x32_bf16(af[i], bfr[j], acc[i][j], 0, 0, 0);
        __builtin_amdgcn_s_setprio(0);
        // ---- phase B: B cols 4..7; stage remaining 2 ----
#pragma unroll
        for (int j = 4; j < 8; ++j)
            bfr[j] = *(const s8v*)(buf + 8192 + (wc * 128 + j * 16 + lc) * 64 + cs);
        if (pf) STAGE_P1(t + 2);
        asm volatile("s_waitcnt lgkmcnt(0)" ::: "memory");
        __builtin_amdgcn_sched_barrier(0);
        __builtin_amdgcn_s_setprio(1);
#pragma unroll
        for (int i = 0; i < 4; ++i)
#pragma unroll
            for (int j = 4; j < 8; ++j)
                acc[i][j] = __builtin_amdgcn_mfma_f32_16x16x32_bf16(af[i], bfr[j], acc[i][j], 0, 0, 0);
        __builtin_amdgcn_s_setprio(0);
        if (pf) {
            asm volatile("s_waitcnt vmcnt(6)" ::: "memory");
        } else if (t + 1 < NT) {
            asm volatile("s_waitcnt vmcnt(0)" ::: "memory");
        }
        __builtin_amdgcn_s_barrier();
    }

    // ---- epilogue: LDS bounce -> coalesced stores (wave: 64 x 128) ----
    float* esc = (float*)smem + w * 2112;   // per-wave 16 rows x 132 words
#pragma unroll
    for (int i = 0; i < 4; ++i) {
#pragma unroll
        for (int j = 0; j < 8; ++j)
#pragma unroll
            for (int r = 0; r < 4; ++r)
                esc[(lq * 4 + r) * 132 + j * 16 + lc] = acc[i][j][r];
#pragma unroll
        for (int p = 0; p < 4; ++p) {
            int rr = p * 4 + lq;
            int row = m0 + wr * 64 + i * 16 + rr;
#pragma unroll
            for (int h = 0; h < 2; ++h) {
                float4 v = *(const float4*)(esc + rr * 132 + h * 64 + lc * 4);
                int col = n0 + wc * 128 + h * 64 + lc * 4;
                float4 bv = *(const float4*)(bias + col);
                v.x += bv.x; v.y += bv.y; v.z += bv.z; v.w += bv.w;
                size_t idx = (size_t)row * N + col;
                ushort4 o;
                if (EPI == 0) {
                    float scl = (col < scaleN) ? SCQ : 1.0f;
                    o.x = f2bf(v.x * scl); o.y = f2bf(v.y * scl);
                    o.z = f2bf(v.z * scl); o.w = f2bf(v.w * scl);
                } else {
                    o.x = f2bf(fgelu(v.x)); o.y = f2bf(fgelu(v.y));
                    o.z = f2bf(fgelu(v.z)); o.w = f2bf(fgelu(v.w));
                }
                *(ushort4*)((unsigned short*)outv + idx) = o;
            }
        }
    }
}

// ---------------- fused flash attention (d=64, 64x64 tiles, 4 waves) ----------
// Swapped QK^T (Q pre-scaled by SCQ); defer-max (THR=8); P->bf16 via
// v_cvt_pk_bf16_f32; double-buffered K/V async-stage split.
// CAUSAL: mirrored q-tile pairing {pr, nqt-1-pr} (balanced 17 tile-rounds).
// Non-causal: one q-tile per block (grid nqt*B*H, max TLP).
template <bool CAUSAL>
__global__ __launch_bounds__(256) void k_attn(
        const unsigned short* __restrict__ Q, int ldq,
        const unsigned short* __restrict__ Kp, int ldk,
        const unsigned short* __restrict__ Vp, int ldv,
        unsigned short* __restrict__ O, int ldo, int T) {
    __shared__ unsigned short Ks[2][64 * 64];  // [t][d], chunk-swizzled
    __shared__ unsigned short Vt[2][64 * 64];  // [d][t], chunk-swizzled
    __shared__ unsigned short Ps[4][16 * 64];  // per-wave P [q16][k64], swizzled
    int nqt = T >> 6;
    int qt0, qt1, bh;
    if (CAUSAL) {
        int pairs = nqt >> 1;
        int pr = blockIdx.x % pairs;
        bh = blockIdx.x / pairs;
        qt0 = pr; qt1 = nqt - 1 - pr;
    } else {
        qt1 = blockIdx.x % nqt;
        bh = blockIdx.x / nqt;
        qt0 = 0;
    }
    int b = bh >> 4, h = bh & 15;
    int tid = threadIdx.x, w = tid >> 6, l = tid & 63;
    int lq = l >> 4, lc = l & 15;
    size_t qoff = (size_t)b * T * ldq + h * 64;
    size_t koff = (size_t)b * T * ldk + h * 64;
    size_t voff = (size_t)b * T * ldv + h * 64;
    s8v qf1[2], qf0[2];
    {
        const unsigned short* qp = Q + qoff + (size_t)(qt1 * 64 + w * 16 + lc) * ldq + lq * 8;
        qf1[0] = *(const s8v*)qp;
        qf1[1] = *(const s8v*)(qp + 32);
        if (CAUSAL) {
            const unsigned short* q0p = Q + qoff + (size_t)(qt0 * 64 + w * 16 + lc) * ldq + lq * 8;
            qf0[0] = *(const s8v*)q0p;
            qf0[1] = *(const s8v*)(q0p + 32);
        }
    }
    s8v ones;
#pragma unroll
    for (int i = 0; i < 8; ++i) ones[i] = (short)0x3F80;   // bf16 1.0
    f4v o1[4], o0[4];
    float l1r[4], l0r[4];
    float m1 = -3.0e38f, m0 = -3.0e38f;
#pragma unroll
    for (int j = 0; j < 4; ++j) {
        o1[j] = fzero(); o0[j] = fzero(); l1r[j] = 0.f; l0r[j] = 0.f;
    }
    int p = tid & 31, dbase = (tid >> 5) * 8;
    s8v v0r, v1r;   // V staging registers

    auto STAGE_K = [&](int kt, int bufi) {
#pragma unroll
        for (int s = 0; s < 2; ++s) {
            int idx = s * 256 + w * 64 + l;
            int t = idx >> 3;
            int ch = (idx & 7) ^ (t & 7);
            gload16(Kp + koff + (size_t)(kt * 64 + t) * ldk + ch * 8,
                    (char*)Ks[bufi] + s * 4096 + w * 1024);
        }
    };
    auto LOAD_V = [&](int kt) {
        const unsigned short* vp = Vp + voff + (size_t)(kt * 64 + 2 * p) * ldv + dbase;
        v0r = *(const s8v*)vp;
        v1r = *(const s8v*)(vp + ldv);
    };
    auto WRITE_V = [&](int bufi) {
#pragma unroll
        for (int j = 0; j < 8; ++j) {
            int dd = dbase + j;
            unsigned int val = (unsigned short)v0r[j] | ((unsigned)(unsigned short)v1r[j] << 16);
            *(unsigned int*)((char*)Vt[bufi] + dd * 128 +
                             ((((p >> 2) ^ (dd & 7)) << 4) | ((p & 3) << 2))) = val;
        }
    };

    // softmax + PV for one q-tile (swapped-S layout: thread owns q = w*16+lc)
    auto SMPV = [&](f4v (&sa)[4], f4v (&oa)[4], float& mr, float (&lr)[4],
                    int bufi, int qt, int kt) {
        bool diag = CAUSAL && (kt == qt);
        int qloc = w * 16 + lc;
        float pv[16];
#pragma unroll
        for (int jn = 0; jn < 4; ++jn)
#pragma unroll
            for (int j = 0; j < 4; ++j) {
                float sv = sa[jn][j];   // S already scaled (Q pre-scaled)
                if (diag && (jn * 16 + lq * 4 + j > qloc)) sv = -3.0e38f;
                pv[jn * 4 + j] = sv;
            }
        // tree max (depth 4) instead of serial chain
        float t8[8];
#pragma unroll
        for (int i = 0; i < 8; ++i) t8[i] = fmaxf(pv[2 * i], pv[2 * i + 1]);
        float t4a = fmaxf(t8[0], t8[1]), t4b = fmaxf(t8[2], t8[3]);
        float t4c = fmaxf(t8[4], t8[5]), t4d = fmaxf(t8[6], t8[7]);
        float tm = fmaxf(fmaxf(t4a, t4b), fmaxf(t4c, t4d));
        tm = fmaxf(tm, __shfl_xor(tm, 16));
        tm = fmaxf(tm, __shfl_xor(tm, 32));
        // ---- defer-max (T13): rescale only if max grew by > 8 (P <= 2^8) ----
        if (!__all(tm <= mr + 8.0f)) {
            float mnew = fmaxf(mr, tm);
            float alpha = exp2f(mr - mnew);
            mr = mnew;
#pragma unroll
            for (int j = 0; j < 4; ++j) {
                float aj = __shfl(alpha, lq * 4 + j);
                lr[j] *= aj;
#pragma unroll
                for (int jn = 0; jn < 4; ++jn) oa[jn][j] *= aj;
            }
        }
        // P write: exp2 + v_cvt_pk_bf16_f32, one 8B write per jn
#pragma unroll
        for (int jn = 0; jn < 4; ++jn) {
            float e0 = exp2f(pv[jn * 4 + 0] - mr);
            float e1 = exp2f(pv[jn * 4 + 1] - mr);
            float e2 = exp2f(pv[jn * 4 + 2] - mr);
            float e3 = exp2f(pv[jn * 4 + 3] - mr);
            unsigned r0, r1;
            asm("v_cvt_pk_bf16_f32 %0, %1, %2" : "=v"(r0) : "v"(e0), "v"(e1));
            asm("v_cvt_pk_bf16_f32 %0, %1, %2" : "=v"(r1) : "v"(e2), "v"(e3));
            int chunk = (jn * 2 + (lq >> 1)) ^ (lc & 7);
            char* basep = (char*)Ps[w] + lc * 128 + (chunk << 4) + ((lq & 1) << 3);
            uint2 rr; rr.x = r0; rr.y = r1;
            *(uint2*)basep = rr;
        }
        // PA fragments + ones-MFMA row sum + PV accumulate
        s8v pa[2];
#pragma unroll
        for (int kc = 0; kc < 2; ++kc)
            pa[kc] = *(const s8v*)((const char*)Ps[w] + lc * 128 +
                                   (((kc * 4 + lq) ^ (lc & 7)) << 4));
        f4v sone = fzero();
        __builtin_amdgcn_s_setprio(1);
#pragma unroll
        for (int kc = 0; kc < 2; ++kc) {
            sone = __builtin_amdgcn_mfma_f32_16x16x32_bf16(pa[kc], ones, sone, 0, 0, 0);
#pragma unroll
            for (int jn = 0; jn < 4; ++jn) {
                int dd = jn * 16 + lc;
                s8v bf = *(const s8v*)((const char*)Vt[bufi] + dd * 128 +
                                       (((kc * 4 + lq) ^ (dd & 7)) << 4));
                oa[jn] = __builtin_amdgcn_mfma_f32_16x16x32_bf16(pa[kc], bf, oa[jn], 0, 0, 0);
            }
        }
        __builtin_amdgcn_s_setprio(0);
#pragma unroll
        for (int j = 0; j < 4; ++j) lr[j] += sone[j];
    };

    int ktend = CAUSAL ? (qt1 + 1) : nqt;
    STAGE_K(0, 0); LOAD_V(0);
    asm volatile("s_waitcnt vmcnt(0)" ::: "memory");
    WRITE_V(0);
    __syncthreads();
    int buf = 0;
    for (int kt = 0; kt < ktend; ++kt) {
        bool pf = (kt + 1 < ktend);
        if (pf) { STAGE_K(kt + 1, buf ^ 1); LOAD_V(kt + 1); }
        bool do0 = CAUSAL && (kt <= qt0);
        f4v sa1[4], sa0[4];
        __builtin_amdgcn_s_setprio(1);
#pragma unroll
        for (int jn = 0; jn < 4; ++jn) {
            sa1[jn] = fzero(); sa0[jn] = fzero();
            int t = jn * 16 + lc;
#pragma unroll
            for (int kc = 0; kc < 2; ++kc) {
                s8v kf = *(const s8v*)((const char*)Ks[buf] + t * 128 +
                                       (((kc * 4 + lq) ^ (t & 7)) << 4));
                sa1[jn] = __builtin_amdgcn_mfma_f32_16x16x32_bf16(kf, qf1[kc], sa1[jn], 0, 0, 0);
                if (do0)
                    sa0[jn] = __builtin_amdgcn_mfma_f32_16x16x32_bf16(kf, qf0[kc], sa0[jn], 0, 0, 0);
            }
        }
        __builtin_amdgcn_s_setprio(0);
        SMPV(sa1, o1, m1, l1r, buf, qt1, kt);
        if (do0) SMPV(sa0, o0, m0, l0r, buf, qt0, kt);
        if (pf) {
            asm volatile("s_waitcnt vmcnt(0)" ::: "memory");
            WRITE_V(buf ^ 1);
        }
        __syncthreads();
        buf ^= 1;
    }
#pragma unroll
    for (int j = 0; j < 4; ++j) {
        float inv = 1.0f / l1r[j];
        int row = qt1 * 64 + w * 16 + lq * 4 + j;
#pragma unroll
        for (int jn = 0; jn < 4; ++jn)
            O[(size_t)(b * T + row) * ldo + h * 64 + jn * 16 + lc] = f2bf(o1[jn][j] * inv);
    }
    if (CAUSAL) {
#pragma unroll
        for (int j = 0; j < 4; ++j) {
            float inv = 1.0f / l0r[j];
            int row = qt0 * 64 + w * 16 + lq * 4 + j;
#pragma unroll
            for (int jn = 0; jn < 4; ++jn)
                O[(size_t)(b * T + row) * ldo + h * 64 + jn * 16 + lc] = f2bf(o0[jn][j] * inv);
        }
    }
}

// ---------------- orchestration ----------------
extern "C" void kernel_launch(void* const* d_in, const int* in_sizes, int n_in,
                              void* d_out, int out_size, void* d_ws, size_t ws_size,
                              hipStream_t stream) {
    const float* x     = (const float*)d_in[0];
    const float* ctx   = (const float*)d_in[1];
    const float* ln1_g = (const float*)d_in[2];
    const float* ln1_b = (const float*)d_in[3];
    const float* ln2_g = (const float*)d_in[4];
    const float* ln2_b = (const float*)d_in[5];
    const float* sa_wq = (const float*)d_in[6];  const float* sa_bq = (const float*)d_in[7];
    const float* sa_wk = (const float*)d_in[8];  const float* sa_bk = (const float*)d_in[9];
    const float* sa_wv = (const float*)d_in[10]; const float* sa_bv = (const float*)d_in[11];
    const float* sa_wo = (const float*)d_in[12]; const float* sa_bo = (const float*)d_in[13];
    const float* ca_wq = (const float*)d_in[14]; const float* ca_bq = (const float*)d_in[15];
    const float* ca_wk = (const float*)d_in[16]; const float* ca_bk = (const float*)d_in[17];
    const float* ca_wv = (const float*)d_in[18]; const float* ca_bv = (const float*)d_in[19];
    const float* ca_wo = (const float*)d_in[20]; const float* ca_bo = (const float*)d_in[21];
    const float* w1 = (const float*)d_in[22]; const float* b1 = (const float*)d_in[23];
    const float* w2 = (const float*)d_in[24]; const float* b2 = (const float*)d_in[25];
    float* out = (float*)d_out;

    char* ws = (char*)d_ws;
    const size_t MB = 1024 * 1024;
    unsigned short* wt_base = (unsigned short*)(ws + 0 * MB);  // 8 x 2MB, order below
    unsigned short* wt_saq = wt_base + 0 * 1024 * 1024;
    unsigned short* wt_cak = wt_base + 5 * 1024 * 1024;        // cak,cav contiguous
    unsigned short* wt_sao = wt_base + 3 * 1024 * 1024;
    unsigned short* wt_caq = wt_base + 4 * 1024 * 1024;
    unsigned short* wt_cao = wt_base + 7 * 1024 * 1024;
    unsigned short* w1t    = (unsigned short*)(ws + 16 * MB);  // 8MB (4096,1024)
    unsigned short* w2t    = (unsigned short*)(ws + 24 * MB);  // 8MB (1024,4096)
    unsigned short* ctxb   = (unsigned short*)(ws + 32 * MB);  // 8MB; reused as h3 in MLP
    float*          x1     = (float*)        (ws + 40 * MB);   // 16MB
    unsigned short* qbuf   = (unsigned short*)(ws + 56 * MB);  // 8MB, start of qkv region
    unsigned short* kbuf   = (unsigned short*)(ws + 64 * MB);  // 8MB, kv region
    unsigned short* hln    = (unsigned short*)(ws + 80 * MB);  // 8MB (ln out / attn out)
    float*          bcat   = (float*)        (ws + 88 * MB);   // 20KB
    unsigned short* qkv = qbuf;   // (4096,3072) spans 56..80MB
    unsigned short* kv  = kbuf;   // (4096,2048) spans 64..80MB
    unsigned short* m1  = qbuf;   // (4096,4096) = 32MB spans 56..88MB
    unsigned short* h3  = ctxb;

    dim3 blk(256);
    // weight prep: 8 square transposes fused; order matches wt_base slots:
    // [saq, sak, sav, sao, caq, cak, cav, cao]
    P8 ws8;
    ws8.p[0] = sa_wq; ws8.p[1] = sa_wk; ws8.p[2] = sa_wv; ws8.p[3] = sa_wo;
    ws8.p[4] = ca_wq; ws8.p[5] = ca_wk; ws8.p[6] = ca_wv; ws8.p[7] = ca_wo;
    k_transpose8<<<dim3(32, 32, 8), blk, 0, stream>>>(ws8, wt_base);
    k_transpose_bf16<<<dim3(128, 32), blk, 0, stream>>>(w1, w1t, 1024, 4096);
    k_transpose_bf16<<<dim3(32, 128), blk, 0, stream>>>(w2, w2t, 4096, 1024);
    k_f32_to_bf16<<<dim3(2048), blk, 0, stream>>>(ctx, ctxb, 4 * 1024 * 1024);
    k_bias_cat<<<dim3(20), blk, 0, stream>>>(sa_bq, sa_bk, sa_bv, ca_bk, ca_bv, bcat);

    // ---- self attention: x1 = x + Wo(attn(ln1(x))) ----
    k_layernorm<<<dim3(4096), blk, 0, stream>>>(x, ln1_g, ln1_b, hln);
    k_gemm<0, 128><<<dim3(768), blk, 0, stream>>>(hln, wt_saq, bcat, nullptr, qkv, 4096, 3072, 1024, 1024);
    k_attn<true><<<dim3(512), blk, 0, stream>>>(qkv, 3072, qkv + 1024, 3072, qkv + 2048, 3072,
                                                hln, 1024, 1024);
    k_gemm<2, 64><<<dim3(64 * 8), blk, 0, stream>>>(hln, wt_sao, sa_bo, x, x1, 4096, 1024, 1024, 0);

    // ---- cross attention: x2 = x1 + Wo(attn(ln2(x1), ctx)) ----
    k_layernorm<<<dim3(4096), blk, 0, stream>>>(x1, ln2_g, ln2_b, hln);
    k_gemm<0, 64><<<dim3(64 * 8), blk, 0, stream>>>(hln, wt_caq, ca_bq, nullptr, qbuf, 4096, 1024, 1024, 1024);
    k_gemm<0, 128><<<dim3(16 * 32), blk, 0, stream>>>(ctxb, wt_cak, bcat + 3072, nullptr, kv, 4096, 2048, 1024, 0);
    k_attn<false><<<dim3(1024), blk, 0, stream>>>(qbuf, 1024, kv, 2048, kv + 1024, 2048,
                                                  hln, 1024, 1024);
    k_gemm<2, 64><<<dim3(64 * 8), blk, 0, stream>>>(hln, wt_cao, ca_bo, x1, out, 4096, 1024, 1024, 0);

    // ---- MLP: out = x2 + W2(gelu(W1(ln2(x2)))) ----
    k_layernorm<<<dim3(4096), blk, 0, stream>>>(out, ln2_g, ln2_b, h3);
    k_gemm2<1><<<dim3(32 * 16), blk, 0, stream>>>(h3, w1t, b1, m1, 4096, 4096, 1024, 0);
    k_gemm<2, 64><<<dim3(64 * 8), blk, 0, stream>>>(m1, w2t, b2, out, out, 4096, 1024, 4096, 0);
}

// Round 15
// 332.909 us; speedup vs baseline: 1.0161x; 1.0161x over previous
//
#include <hip/hip_runtime.h>
#include <hip/hip_bf16.h>

typedef __attribute__((ext_vector_type(8))) short s8v;   // 8 x bf16 (bit pattern)
typedef __attribute__((ext_vector_type(4))) float f4v;   // MFMA accumulator

#define DEV static __device__ __forceinline__

__device__ const float SCQ = 0.18033688011112042f;   // (1/8) * log2(e)

DEV unsigned short f2bf(float f) {
    unsigned int u = __builtin_bit_cast(unsigned int, f);
    unsigned int r = u + 0x7FFFu + ((u >> 16) & 1u);
    return (unsigned short)(r >> 16);
}

DEV f4v fzero() { f4v v = {0.f, 0.f, 0.f, 0.f}; return v; }

// fast GELU (tanh form): x * sigmoid(1.5957691*(x + 0.044715 x^3))
DEV float fgelu(float x) {
    float z = x * (1.5957691f + 0.07135482f * x * x);
    float s = __builtin_amdgcn_rcpf(1.0f + __expf(-z));
    return x * s;
}

DEV void gload16(const void* g, void* l) {
    __builtin_amdgcn_global_load_lds(
        (const __attribute__((address_space(1))) unsigned int*)g,
        (__attribute__((address_space(3))) unsigned int*)l, 16, 0, 0);
}

// ---------------- fused transpose of 8 (1024,1024) f32 weights -> bf16 -----
struct P8 { const float* p[8]; };
__global__ __launch_bounds__(256) void k_transpose8(
        P8 ws8, unsigned short* __restrict__ base) {
    __shared__ float tile[32][33];
    int z = blockIdx.z;
    const float* W = ws8.p[z];
    unsigned short* Wt = base + (size_t)z * 1024 * 1024;
    int tx = threadIdx.x & 31, ty = threadIdx.x >> 5;
    int n0 = blockIdx.x * 32, k0 = blockIdx.y * 32;
#pragma unroll
    for (int r = 0; r < 32; r += 8)
        tile[ty + r][tx] = W[(size_t)(k0 + ty + r) * 1024 + n0 + tx];
    __syncthreads();
#pragma unroll
    for (int r = 0; r < 32; r += 8)
        Wt[(size_t)(n0 + ty + r) * 1024 + k0 + tx] = f2bf(tile[tx][ty + r]);
}

// ---------------- weight transpose f32 (K,N) -> bf16 (N,K) ----------------
__global__ __launch_bounds__(256) void k_transpose_bf16(
        const float* __restrict__ W, unsigned short* __restrict__ Wt, int K, int N) {
    __shared__ float tile[32][33];
    int tx = threadIdx.x & 31, ty = threadIdx.x >> 5;
    int n0 = blockIdx.x * 32, k0 = blockIdx.y * 32;
#pragma unroll
    for (int r = 0; r < 32; r += 8)
        tile[ty + r][tx] = W[(size_t)(k0 + ty + r) * N + n0 + tx];
    __syncthreads();
#pragma unroll
    for (int r = 0; r < 32; r += 8)
        Wt[(size_t)(n0 + ty + r) * K + k0 + tx] = f2bf(tile[tx][ty + r]);
}

// ---------------- elementwise f32 -> bf16 ----------------
__global__ __launch_bounds__(256) void k_f32_to_bf16(
        const float* __restrict__ in, unsigned short* __restrict__ out, int n) {
    int i = (blockIdx.x * 256 + threadIdx.x) * 8;
    if (i >= n) return;
    float4 a = *(const float4*)(in + i);
    float4 b = *(const float4*)(in + i + 4);
    uint4 o;
    o.x = f2bf(a.x) | ((unsigned)f2bf(a.y) << 16);
    o.y = f2bf(a.z) | ((unsigned)f2bf(a.w) << 16);
    o.z = f2bf(b.x) | ((unsigned)f2bf(b.y) << 16);
    o.w = f2bf(b.z) | ((unsigned)f2bf(b.w) << 16);
    *(uint4*)(out + i) = o;
}

// ---------------- bias concat: [sa_bq|sa_bk|sa_bv|ca_bk|ca_bv] ----------------
__global__ __launch_bounds__(256) void k_bias_cat(
        const float* q, const float* k, const float* v,
        const float* k2, const float* v2, float* out) {
    int i = blockIdx.x * 256 + threadIdx.x;  // 5120 total
    float val;
    if (i < 1024) val = q[i];
    else if (i < 2048) val = k[i - 1024];
    else if (i < 3072) val = v[i - 2048];
    else if (i < 4096) val = k2[i - 3072];
    else val = v2[i - 4096];
    out[i] = val;
}

// ---------------- LayerNorm f32 -> bf16 (C=1024) ----------------
__global__ __launch_bounds__(256) void k_layernorm(
        const float* __restrict__ x, const float* __restrict__ g,
        const float* __restrict__ b, unsigned short* __restrict__ out) {
    int row = blockIdx.x;
    int t = threadIdx.x;
    const float* xr = x + (size_t)row * 1024;
    float4 v = *(const float4*)(xr + t * 4);
    float s = v.x + v.y + v.z + v.w;
    float ss = v.x * v.x + v.y * v.y + v.z * v.z + v.w * v.w;
#pragma unroll
    for (int m = 1; m < 64; m <<= 1) { s += __shfl_xor(s, m); ss += __shfl_xor(ss, m); }
    __shared__ float red[16];
    int w = t >> 6;
    if ((t & 63) == 0) { red[w] = s; red[8 + w] = ss; }
    __syncthreads();
    s = red[0] + red[1] + red[2] + red[3];
    ss = red[8] + red[9] + red[10] + red[11];
    float mu = s * (1.f / 1024.f);
    float rstd = rsqrtf(ss * (1.f / 1024.f) - mu * mu + 1e-5f);
    float4 gv = *(const float4*)(g + t * 4);
    float4 bv = *(const float4*)(b + t * 4);
    float y0 = (v.x - mu) * rstd * gv.x + bv.x;
    float y1 = (v.y - mu) * rstd * gv.y + bv.y;
    float y2 = (v.z - mu) * rstd * gv.z + bv.z;
    float y3 = (v.w - mu) * rstd * gv.w + bv.w;
    uint2 o;
    o.x = f2bf(y0) | ((unsigned)f2bf(y1) << 16);
    o.y = f2bf(y2) | ((unsigned)f2bf(y3) << 16);
    *(uint2*)(out + (size_t)row * 1024 + t * 4) = o;
}

// ============ GEMM v1: 128/64 x 128 tile ===================================
// 3-buffer counted-vmcnt pipeline, chunk-XOR LDS swizzle w/ pre-swizzled
// source, XCD swizzle, setprio MFMA cluster, LDS-bounce epilogue.
// EPI 0: bf16+bias (cols<scaleN get x SCQ)  1: bf16 fgelu  2: f32 res+acc+bias
template <int EPI, int BM>
__global__ __launch_bounds__(256) void k_gemm(
        const unsigned short* __restrict__ A, const unsigned short* __restrict__ Bt,
        const float* __restrict__ bias, const float* __restrict__ res,
        void* __restrict__ outv, int M, int N, int K, int scaleN) {
    constexpr int WI = (BM == 128) ? 4 : 2;       // 16-row frags per wave
    constexpr int ABUF = BM * 64;                 // bytes per A buffer
    constexpr int BUFSZ = ABUF + 8192;            // A + B per K-tile
    __shared__ __align__(16) char smem[3 * BUFSZ];
    int nbx = N >> 7;
    int bid = blockIdx.x;
    int cpx = gridDim.x >> 3;          // all grids are %8 == 0
    int swz = (bid & 7) * cpx + (bid >> 3);
    int bx = swz % nbx, by = swz / nbx;
    int m0 = by * BM, n0 = bx << 7;
    int tid = threadIdx.x, w = tid >> 6, l = tid & 63;
    int wr = w >> 1, wc = w & 1;
    int lq = l >> 4, lc = l & 15;
    f4v acc[WI][4];
#pragma unroll
    for (int i = 0; i < WI; ++i)
#pragma unroll
        for (int j = 0; j < 4; ++j) acc[i][j] = fzero();
    const unsigned short* Ab = A + (size_t)m0 * K;
    const unsigned short* Bb = Bt + (size_t)n0 * K;
    int arow = w * 16 + (l >> 2);                       // 0..63
    int ach = (((l & 3) ^ ((arow >> 1) & 3)) << 3);     // pre-swizzled k-chunk

    auto STAGE = [&](int t) {
        int kt = t << 5;
        char* buf = smem + (t % 3) * BUFSZ;
        gload16(Ab + (size_t)arow * K + kt + ach, buf + w * 1024);
        if constexpr (BM == 128)
            gload16(Ab + (size_t)(64 + arow) * K + kt + ach, buf + 4096 + w * 1024);
        gload16(Bb + (size_t)arow * K + kt + ach, buf + ABUF + w * 1024);
        gload16(Bb + (size_t)(64 + arow) * K + kt + ach, buf + ABUF + 4096 + w * 1024);
    };
    int cs = ((lq ^ ((lc >> 1) & 3)) << 4);             // read-side swizzle
    auto COMPUTE = [&](int t) {
        const char* buf = smem + (t % 3) * BUFSZ;
        s8v af[WI], bfr[4];
#pragma unroll
        for (int i = 0; i < WI; ++i)
            af[i] = *(const s8v*)(buf + (wr * (BM / 2) + i * 16 + lc) * 64 + cs);
#pragma unroll
        for (int j = 0; j < 4; ++j)
            bfr[j] = *(const s8v*)(buf + ABUF + (wc * 64 + j * 16 + lc) * 64 + cs);
        __builtin_amdgcn_s_setprio(1);
#pragma unroll
        for (int i = 0; i < WI; ++i)
#pragma unroll
            for (int j = 0; j < 4; ++j)
                acc[i][j] = __builtin_amdgcn_mfma_f32_16x16x32_bf16(af[i], bfr[j], acc[i][j], 0, 0, 0);
        __builtin_amdgcn_s_setprio(0);
    };

    int NT = K >> 5;
    STAGE(0); STAGE(1);
    if constexpr (BM == 128) asm volatile("s_waitcnt vmcnt(4)" ::: "memory");
    else                     asm volatile("s_waitcnt vmcnt(3)" ::: "memory");
    __builtin_amdgcn_s_barrier();
    for (int t = 0; t < NT; ++t) {
        if (t + 2 < NT) STAGE(t + 2);
        COMPUTE(t);
        if (t + 2 < NT) {
            if constexpr (BM == 128) asm volatile("s_waitcnt vmcnt(4)" ::: "memory");
            else                     asm volatile("s_waitcnt vmcnt(3)" ::: "memory");
        } else if (t + 1 < NT) {
            asm volatile("s_waitcnt vmcnt(0)" ::: "memory");
        }
        __builtin_amdgcn_s_barrier();
    }

    // ---- epilogue: LDS bounce -> coalesced 8/16B stores ----
    float* esc = (float*)smem + w * 1088;   // per-wave 16 rows x 68 words
#pragma unroll
    for (int i = 0; i < WI; ++i) {
#pragma unroll
        for (int j = 0; j < 4; ++j)
#pragma unroll
            for (int r = 0; r < 4; ++r)
                esc[(lq * 4 + r) * 68 + j * 16 + lc] = acc[i][j][r];
#pragma unroll
        for (int p = 0; p < 4; ++p) {
            int rr = p * 4 + lq;
            float4 v = *(const float4*)(esc + rr * 68 + lc * 4);
            int row = m0 + wr * (BM / 2) + i * 16 + rr;
            int col = n0 + wc * 64 + lc * 4;
            float4 bv = *(const float4*)(bias + col);
            v.x += bv.x; v.y += bv.y; v.z += bv.z; v.w += bv.w;
            size_t idx = (size_t)row * N + col;
            if (EPI == 0) {
                float scl = (col < scaleN) ? SCQ : 1.0f;
                ushort4 o;
                o.x = f2bf(v.x * scl); o.y = f2bf(v.y * scl);
                o.z = f2bf(v.z * scl); o.w = f2bf(v.w * scl);
                *(ushort4*)((unsigned short*)outv + idx) = o;
            } else if (EPI == 1) {
                ushort4 o;
                o.x = f2bf(fgelu(v.x)); o.y = f2bf(fgelu(v.y));
                o.z = f2bf(fgelu(v.z)); o.w = f2bf(fgelu(v.w));
                *(ushort4*)((unsigned short*)outv + idx) = o;
            } else {
                float4 rv = *(const float4*)(res + idx);
                v.x += rv.x; v.y += rv.y; v.z += rv.z; v.w += rv.w;
                *(float4*)((float*)outv + idx) = v;
            }
        }
    }
}

// ============ GEMM v2: 128x256 tile, wave = 64x128 (acc 4x8) ===============
// 2-phase per-tile interleave, 3-buffer counted vmcnt(6), setprio clusters.
// EPI 0: bf16+bias (cols<scaleN get x SCQ)   1: bf16 fgelu
template <int EPI>
__global__ __launch_bounds__(256, 2) void k_gemm2(
        const unsigned short* __restrict__ A, const unsigned short* __restrict__ Bt,
        const float* __restrict__ bias, void* __restrict__ outv,
        int M, int N, int K, int scaleN) {
    constexpr int BUFSZ = 8192 + 16384;   // A(128x64B) + B(256x64B)
    __shared__ __align__(16) char smem[3 * BUFSZ];
    int nbx = N >> 8;
    int bid = blockIdx.x;
    int cpx = gridDim.x >> 3;             // grids are %8 == 0
    int swz = (bid & 7) * cpx + (bid >> 3);
    int bx = swz % nbx, by = swz / nbx;
    int m0 = by << 7, n0 = bx << 8;
    int tid = threadIdx.x, w = tid >> 6, l = tid & 63;
    int wr = w >> 1, wc = w & 1;
    int lq = l >> 4, lc = l & 15;
    f4v acc[4][8];
#pragma unroll
    for (int i = 0; i < 4; ++i)
#pragma unroll
        for (int j = 0; j < 8; ++j) acc[i][j] = fzero();
    const unsigned short* Ab = A + (size_t)m0 * K;
    const unsigned short* Bb = Bt + (size_t)n0 * K;
    int arow = w * 16 + (l >> 2);                       // 0..63
    int ach = (((l & 3) ^ ((arow >> 1) & 3)) << 3);     // pre-swizzled k-chunk

    auto STAGE_P0 = [&](int t) {       // A both halves + B halves 0,1
        int kt = t << 5;
        char* buf = smem + (t % 3) * BUFSZ;
        gload16(Ab + (size_t)arow * K + kt + ach, buf + w * 1024);
        gload16(Ab + (size_t)(64 + arow) * K + kt + ach, buf + 4096 + w * 1024);
        gload16(Bb + (size_t)arow * K + kt + ach, buf + 8192 + w * 1024);
        gload16(Bb + (size_t)(64 + arow) * K + kt + ach, buf + 8192 + 4096 + w * 1024);
    };
    auto STAGE_P1 = [&](int t) {       // B halves 2,3
        int kt = t << 5;
        char* buf = smem + (t % 3) * BUFSZ;
        gload16(Bb + (size_t)(128 + arow) * K + kt + ach, buf + 8192 + 8192 + w * 1024);
        gload16(Bb + (size_t)(192 + arow) * K + kt + ach, buf + 8192 + 12288 + w * 1024);
    };
    int cs = ((lq ^ ((lc >> 1) & 3)) << 4);             // read-side swizzle

    int NT = K >> 5;
    STAGE_P0(0); STAGE_P1(0); STAGE_P0(1); STAGE_P1(1);
    asm volatile("s_waitcnt vmcnt(6)" ::: "memory");
    __builtin_amdgcn_s_barrier();
    for (int t = 0; t < NT; ++t) {
        const char* buf = smem + (t % 3) * BUFSZ;
        bool pf = (t + 2 < NT);
        // ---- phase A: A frags + B cols 0..3; stage 4 of 6 ----
        s8v af[4], bfr[8];
#pragma unroll
        for (int i = 0; i < 4; ++i)
            af[i] = *(const s8v*)(buf + (wr * 64 + i * 16 + lc) * 64 + cs);
#pragma unroll
        for (int j = 0; j < 4; ++j)
            bfr[j] = *(const s8v*)(buf + 8192 + (wc * 128 + j * 16 + lc) * 64 + cs);
        if (pf) STAGE_P0(t + 2);
        asm volatile("s_waitcnt lgkmcnt(0)" ::: "memory");
        __builtin_amdgcn_sched_barrier(0);
        __builtin_amdgcn_s_setprio(1);
#pragma unroll
        for (int i = 0; i < 4; ++i)
#pragma unroll
            for (int j = 0; j < 4; ++j)
                acc[i][j] = __builtin_amdgcn_mfma_f32_16x16x32_bf16(af[i], bfr[j], acc[i][j], 0, 0, 0);
        __builtin_amdgcn_s_setprio(0);
        // ---- phase B: B cols 4..7; stage remaining 2 ----
#pragma unroll
        for (int j = 4; j < 8; ++j)
            bfr[j] = *(const s8v*)(buf + 8192 + (wc * 128 + j * 16 + lc) * 64 + cs);
        if (pf) STAGE_P1(t + 2);
        asm volatile("s_waitcnt lgkmcnt(0)" ::: "memory");
        __builtin_amdgcn_sched_barrier(0);
        __builtin_amdgcn_s_setprio(1);
#pragma unroll
        for (int i = 0; i < 4; ++i)
#pragma unroll
            for (int j = 4; j < 8; ++j)
                acc[i][j] = __builtin_amdgcn_mfma_f32_16x16x32_bf16(af[i], bfr[j], acc[i][j], 0, 0, 0);
        __builtin_amdgcn_s_setprio(0);
        if (pf) {
            asm volatile("s_waitcnt vmcnt(6)" ::: "memory");
        } else if (t + 1 < NT) {
            asm volatile("s_waitcnt vmcnt(0)" ::: "memory");
        }
        __builtin_amdgcn_s_barrier();
    }

    // ---- epilogue: LDS bounce -> coalesced stores (wave: 64 x 128) ----
    float* esc = (float*)smem + w * 2112;   // per-wave 16 rows x 132 words
#pragma unroll
    for (int i = 0; i < 4; ++i) {
#pragma unroll
        for (int j = 0; j < 8; ++j)
#pragma unroll
            for (int r = 0; r < 4; ++r)
                esc[(lq * 4 + r) * 132 + j * 16 + lc] = acc[i][j][r];
#pragma unroll
        for (int p = 0; p < 4; ++p) {
            int rr = p * 4 + lq;
            int row = m0 + wr * 64 + i * 16 + rr;
#pragma unroll
            for (int h = 0; h < 2; ++h) {
                float4 v = *(const float4*)(esc + rr * 132 + h * 64 + lc * 4);
                int col = n0 + wc * 128 + h * 64 + lc * 4;
                float4 bv = *(const float4*)(bias + col);
                v.x += bv.x; v.y += bv.y; v.z += bv.z; v.w += bv.w;
                size_t idx = (size_t)row * N + col;
                ushort4 o;
                if (EPI == 0) {
                    float scl = (col < scaleN) ? SCQ : 1.0f;
                    o.x = f2bf(v.x * scl); o.y = f2bf(v.y * scl);
                    o.z = f2bf(v.z * scl); o.w = f2bf(v.w * scl);
                } else {
                    o.x = f2bf(fgelu(v.x)); o.y = f2bf(fgelu(v.y));
                    o.z = f2bf(fgelu(v.z)); o.w = f2bf(fgelu(v.w));
                }
                *(ushort4*)((unsigned short*)outv + idx) = o;
            }
        }
    }
}

// ---------------- fused flash attention (d=64, 64x64 tiles, 4 waves) ----------
// Swapped QK^T (Q pre-scaled by SCQ); defer-max (THR=8); P->bf16 via
// v_cvt_pk_bf16_f32; double-buffered K/V async-stage split.
// XCD-aware block swizzle (T1): all q-tiles of one (b,h) land on ONE XCD so
// the K/V panel (256KB) stays L2-resident (8 panels = 2MB < 4MB per-XCD L2).
// CAUSAL: mirrored q-tile pairing {pr, nqt-1-pr} (balanced 17 tile-rounds).
template <bool CAUSAL>
__global__ __launch_bounds__(256) void k_attn(
        const unsigned short* __restrict__ Q, int ldq,
        const unsigned short* __restrict__ Kp, int ldk,
        const unsigned short* __restrict__ Vp, int ldv,
        unsigned short* __restrict__ O, int ldo, int T) {
    __shared__ unsigned short Ks[2][64 * 64];  // [t][d], chunk-swizzled
    __shared__ unsigned short Vt[2][64 * 64];  // [d][t], chunk-swizzled
    __shared__ unsigned short Ps[4][16 * 64];  // per-wave P [q16][k64], swizzled
    int nqt = T >> 6;
    // XCD swizzle: grid %8==0; blocks with the same bh stay on the same XCD.
    int bid = blockIdx.x;
    int cpx = gridDim.x >> 3;
    int swzb = (bid & 7) * cpx + (bid >> 3);
    int qt0, qt1, bh;
    if (CAUSAL) {
        int pairs = nqt >> 1;
        int pr = swzb % pairs;
        bh = swzb / pairs;
        qt0 = pr; qt1 = nqt - 1 - pr;
    } else {
        qt1 = swzb % nqt;
        bh = swzb / nqt;
        qt0 = 0;
    }
    int b = bh >> 4, h = bh & 15;
    int tid = threadIdx.x, w = tid >> 6, l = tid & 63;
    int lq = l >> 4, lc = l & 15;
    size_t qoff = (size_t)b * T * ldq + h * 64;
    size_t koff = (size_t)b * T * ldk + h * 64;
    size_t voff = (size_t)b * T * ldv + h * 64;
    s8v qf1[2], qf0[2];
    {
        const unsigned short* qp = Q + qoff + (size_t)(qt1 * 64 + w * 16 + lc) * ldq + lq * 8;
        qf1[0] = *(const s8v*)qp;
        qf1[1] = *(const s8v*)(qp + 32);
        if (CAUSAL) {
            const unsigned short* q0p = Q + qoff + (size_t)(qt0 * 64 + w * 16 + lc) * ldq + lq * 8;
            qf0[0] = *(const s8v*)q0p;
            qf0[1] = *(const s8v*)(q0p + 32);
        }
    }
    s8v ones;
#pragma unroll
    for (int i = 0; i < 8; ++i) ones[i] = (short)0x3F80;   // bf16 1.0
    f4v o1[4], o0[4];
    float l1r[4], l0r[4];
    float m1 = -3.0e38f, m0 = -3.0e38f;
#pragma unroll
    for (int j = 0; j < 4; ++j) {
        o1[j] = fzero(); o0[j] = fzero(); l1r[j] = 0.f; l0r[j] = 0.f;
    }
    int p = tid & 31, dbase = (tid >> 5) * 8;
    s8v v0r, v1r;   // V staging registers

    auto STAGE_K = [&](int kt, int bufi) {
#pragma unroll
        for (int s = 0; s < 2; ++s) {
            int idx = s * 256 + w * 64 + l;
            int t = idx >> 3;
            int ch = (idx & 7) ^ (t & 7);
            gload16(Kp + koff + (size_t)(kt * 64 + t) * ldk + ch * 8,
                    (char*)Ks[bufi] + s * 4096 + w * 1024);
        }
    };
    auto LOAD_V = [&](int kt) {
        const unsigned short* vp = Vp + voff + (size_t)(kt * 64 + 2 * p) * ldv + dbase;
        v0r = *(const s8v*)vp;
        v1r = *(const s8v*)(vp + ldv);
    };
    auto WRITE_V = [&](int bufi) {
#pragma unroll
        for (int j = 0; j < 8; ++j) {
            int dd = dbase + j;
            unsigned int val = (unsigned short)v0r[j] | ((unsigned)(unsigned short)v1r[j] << 16);
            *(unsigned int*)((char*)Vt[bufi] + dd * 128 +
                             ((((p >> 2) ^ (dd & 7)) << 4) | ((p & 3) << 2))) = val;
        }
    };

    // softmax + PV for one q-tile (swapped-S layout: thread owns q = w*16+lc)
    auto SMPV = [&](f4v (&sa)[4], f4v (&oa)[4], float& mr, float (&lr)[4],
                    int bufi, int qt, int kt) {
        bool diag = CAUSAL && (kt == qt);
        int qloc = w * 16 + lc;
        float pv[16];
#pragma unroll
        for (int jn = 0; jn < 4; ++jn)
#pragma unroll
            for (int j = 0; j < 4; ++j) {
                float sv = sa[jn][j];   // S already scaled (Q pre-scaled)
                if (diag && (jn * 16 + lq * 4 + j > qloc)) sv = -3.0e38f;
                pv[jn * 4 + j] = sv;
            }
        // tree max (depth 4) instead of serial chain
        float t8[8];
#pragma unroll
        for (int i = 0; i < 8; ++i) t8[i] = fmaxf(pv[2 * i], pv[2 * i + 1]);
        float t4a = fmaxf(t8[0], t8[1]), t4b = fmaxf(t8[2], t8[3]);
        float t4c = fmaxf(t8[4], t8[5]), t4d = fmaxf(t8[6], t8[7]);
        float tm = fmaxf(fmaxf(t4a, t4b), fmaxf(t4c, t4d));
        tm = fmaxf(tm, __shfl_xor(tm, 16));
        tm = fmaxf(tm, __shfl_xor(tm, 32));
        // ---- defer-max (T13): rescale only if max grew by > 8 (P <= 2^8) ----
        if (!__all(tm <= mr + 8.0f)) {
            float mnew = fmaxf(mr, tm);
            float alpha = exp2f(mr - mnew);
            mr = mnew;
#pragma unroll
            for (int j = 0; j < 4; ++j) {
                float aj = __shfl(alpha, lq * 4 + j);
                lr[j] *= aj;
#pragma unroll
                for (int jn = 0; jn < 4; ++jn) oa[jn][j] *= aj;
            }
        }
        // P write: exp2 + v_cvt_pk_bf16_f32, one 8B write per jn
#pragma unroll
        for (int jn = 0; jn < 4; ++jn) {
            float e0 = exp2f(pv[jn * 4 + 0] - mr);
            float e1 = exp2f(pv[jn * 4 + 1] - mr);
            float e2 = exp2f(pv[jn * 4 + 2] - mr);
            float e3 = exp2f(pv[jn * 4 + 3] - mr);
            unsigned r0, r1;
            asm("v_cvt_pk_bf16_f32 %0, %1, %2" : "=v"(r0) : "v"(e0), "v"(e1));
            asm("v_cvt_pk_bf16_f32 %0, %1, %2" : "=v"(r1) : "v"(e2), "v"(e3));
            int chunk = (jn * 2 + (lq >> 1)) ^ (lc & 7);
            char* basep = (char*)Ps[w] + lc * 128 + (chunk << 4) + ((lq & 1) << 3);
            uint2 rr; rr.x = r0; rr.y = r1;
            *(uint2*)basep = rr;
        }
        // PA fragments + ones-MFMA row sum + PV accumulate
        s8v pa[2];
#pragma unroll
        for (int kc = 0; kc < 2; ++kc)
            pa[kc] = *(const s8v*)((const char*)Ps[w] + lc * 128 +
                                   (((kc * 4 + lq) ^ (lc & 7)) << 4));
        f4v sone = fzero();
        __builtin_amdgcn_s_setprio(1);
#pragma unroll
        for (int kc = 0; kc < 2; ++kc) {
            sone = __builtin_amdgcn_mfma_f32_16x16x32_bf16(pa[kc], ones, sone, 0, 0, 0);
#pragma unroll
            for (int jn = 0; jn < 4; ++jn) {
                int dd = jn * 16 + lc;
                s8v bf = *(const s8v*)((const char*)Vt[bufi] + dd * 128 +
                                       (((kc * 4 + lq) ^ (dd & 7)) << 4));
                oa[jn] = __builtin_amdgcn_mfma_f32_16x16x32_bf16(pa[kc], bf, oa[jn], 0, 0, 0);
            }
        }
        __builtin_amdgcn_s_setprio(0);
#pragma unroll
        for (int j = 0; j < 4; ++j) lr[j] += sone[j];
    };

    int ktend = CAUSAL ? (qt1 + 1) : nqt;
    STAGE_K(0, 0); LOAD_V(0);
    asm volatile("s_waitcnt vmcnt(0)" ::: "memory");
    WRITE_V(0);
    __syncthreads();
    int buf = 0;
    for (int kt = 0; kt < ktend; ++kt) {
        bool pf = (kt + 1 < ktend);
        if (pf) { STAGE_K(kt + 1, buf ^ 1); LOAD_V(kt + 1); }
        bool do0 = CAUSAL && (kt <= qt0);
        f4v sa1[4], sa0[4];
        __builtin_amdgcn_s_setprio(1);
#pragma unroll
        for (int jn = 0; jn < 4; ++jn) {
            sa1[jn] = fzero(); sa0[jn] = fzero();
            int t = jn * 16 + lc;
#pragma unroll
            for (int kc = 0; kc < 2; ++kc) {
                s8v kf = *(const s8v*)((const char*)Ks[buf] + t * 128 +
                                       (((kc * 4 + lq) ^ (t & 7)) << 4));
                sa1[jn] = __builtin_amdgcn_mfma_f32_16x16x32_bf16(kf, qf1[kc], sa1[jn], 0, 0, 0);
                if (do0)
                    sa0[jn] = __builtin_amdgcn_mfma_f32_16x16x32_bf16(kf, qf0[kc], sa0[jn], 0, 0, 0);
            }
        }
        __builtin_amdgcn_s_setprio(0);
        SMPV(sa1, o1, m1, l1r, buf, qt1, kt);
        if (do0) SMPV(sa0, o0, m0, l0r, buf, qt0, kt);
        if (pf) {
            asm volatile("s_waitcnt vmcnt(0)" ::: "memory");
            WRITE_V(buf ^ 1);
        }
        __syncthreads();
        buf ^= 1;
    }
#pragma unroll
    for (int j = 0; j < 4; ++j) {
        float inv = 1.0f / l1r[j];
        int row = qt1 * 64 + w * 16 + lq * 4 + j;
#pragma unroll
        for (int jn = 0; jn < 4; ++jn)
            O[(size_t)(b * T + row) * ldo + h * 64 + jn * 16 + lc] = f2bf(o1[jn][j] * inv);
    }
    if (CAUSAL) {
#pragma unroll
        for (int j = 0; j < 4; ++j) {
            float inv = 1.0f / l0r[j];
            int row = qt0 * 64 + w * 16 + lq * 4 + j;
#pragma unroll
            for (int jn = 0; jn < 4; ++jn)
                O[(size_t)(b * T + row) * ldo + h * 64 + jn * 16 + lc] = f2bf(o0[jn][j] * inv);
        }
    }
}

// ---------------- orchestration ----------------
extern "C" void kernel_launch(void* const* d_in, const int* in_sizes, int n_in,
                              void* d_out, int out_size, void* d_ws, size_t ws_size,
                              hipStream_t stream) {
    const float* x     = (const float*)d_in[0];
    const float* ctx   = (const float*)d_in[1];
    const float* ln1_g = (const float*)d_in[2];
    const float* ln1_b = (const float*)d_in[3];
    const float* ln2_g = (const float*)d_in[4];
    const float* ln2_b = (const float*)d_in[5];
    const float* sa_wq = (const float*)d_in[6];  const float* sa_bq = (const float*)d_in[7];
    const float* sa_wk = (const float*)d_in[8];  const float* sa_bk = (const float*)d_in[9];
    const float* sa_wv = (const float*)d_in[10]; const float* sa_bv = (const float*)d_in[11];
    const float* sa_wo = (const float*)d_in[12]; const float* sa_bo = (const float*)d_in[13];
    const float* ca_wq = (const float*)d_in[14]; const float* ca_bq = (const float*)d_in[15];
    const float* ca_wk = (const float*)d_in[16]; const float* ca_bk = (const float*)d_in[17];
    const float* ca_wv = (const float*)d_in[18]; const float* ca_bv = (const float*)d_in[19];
    const float* ca_wo = (const float*)d_in[20]; const float* ca_bo = (const float*)d_in[21];
    const float* w1 = (const float*)d_in[22]; const float* b1 = (const float*)d_in[23];
    const float* w2 = (const float*)d_in[24]; const float* b2 = (const float*)d_in[25];
    float* out = (float*)d_out;

    char* ws = (char*)d_ws;
    const size_t MB = 1024 * 1024;
    unsigned short* wt_base = (unsigned short*)(ws + 0 * MB);  // 8 x 2MB, order below
    unsigned short* wt_saq = wt_base + 0 * 1024 * 1024;
    unsigned short* wt_cak = wt_base + 5 * 1024 * 1024;        // cak,cav contiguous
    unsigned short* wt_sao = wt_base + 3 * 1024 * 1024;
    unsigned short* wt_caq = wt_base + 4 * 1024 * 1024;
    unsigned short* wt_cao = wt_base + 7 * 1024 * 1024;
    unsigned short* w1t    = (unsigned short*)(ws + 16 * MB);  // 8MB (4096,1024)
    unsigned short* w2t    = (unsigned short*)(ws + 24 * MB);  // 8MB (1024,4096)
    unsigned short* ctxb   = (unsigned short*)(ws + 32 * MB);  // 8MB; reused as h3 in MLP
    float*          x1     = (float*)        (ws + 40 * MB);   // 16MB
    unsigned short* qbuf   = (unsigned short*)(ws + 56 * MB);  // 8MB, start of qkv region
    unsigned short* kbuf   = (unsigned short*)(ws + 64 * MB);  // 8MB, kv region
    unsigned short* hln    = (unsigned short*)(ws + 80 * MB);  // 8MB (ln out / attn out)
    float*          bcat   = (float*)        (ws + 88 * MB);   // 20KB
    unsigned short* qkv = qbuf;   // (4096,3072) spans 56..80MB
    unsigned short* kv  = kbuf;   // (4096,2048) spans 64..80MB
    unsigned short* m1  = qbuf;   // (4096,4096) = 32MB spans 56..88MB
    unsigned short* h3  = ctxb;

    dim3 blk(256);
    // weight prep: 8 square transposes fused; order matches wt_base slots:
    // [saq, sak, sav, sao, caq, cak, cav, cao]
    P8 ws8;
    ws8.p[0] = sa_wq; ws8.p[1] = sa_wk; ws8.p[2] = sa_wv; ws8.p[3] = sa_wo;
    ws8.p[4] = ca_wq; ws8.p[5] = ca_wk; ws8.p[6] = ca_wv; ws8.p[7] = ca_wo;
    k_transpose8<<<dim3(32, 32, 8), blk, 0, stream>>>(ws8, wt_base);
    k_transpose_bf16<<<dim3(128, 32), blk, 0, stream>>>(w1, w1t, 1024, 4096);
    k_transpose_bf16<<<dim3(32, 128), blk, 0, stream>>>(w2, w2t, 4096, 1024);
    k_f32_to_bf16<<<dim3(2048), blk, 0, stream>>>(ctx, ctxb, 4 * 1024 * 1024);
    k_bias_cat<<<dim3(20), blk, 0, stream>>>(sa_bq, sa_bk, sa_bv, ca_bk, ca_bv, bcat);

    // ---- self attention: x1 = x + Wo(attn(ln1(x))) ----
    k_layernorm<<<dim3(4096), blk, 0, stream>>>(x, ln1_g, ln1_b, hln);
    k_gemm<0, 128><<<dim3(768), blk, 0, stream>>>(hln, wt_saq, bcat, nullptr, qkv, 4096, 3072, 1024, 1024);
    k_attn<true><<<dim3(512), blk, 0, stream>>>(qkv, 3072, qkv + 1024, 3072, qkv + 2048, 3072,
                                                hln, 1024, 1024);
    k_gemm<2, 64><<<dim3(64 * 8), blk, 0, stream>>>(hln, wt_sao, sa_bo, x, x1, 4096, 1024, 1024, 0);

    // ---- cross attention: x2 = x1 + Wo(attn(ln2(x1), ctx)) ----
    k_layernorm<<<dim3(4096), blk, 0, stream>>>(x1, ln2_g, ln2_b, hln);
    k_gemm<0, 64><<<dim3(64 * 8), blk, 0, stream>>>(hln, wt_caq, ca_bq, nullptr, qbuf, 4096, 1024, 1024, 1024);
    k_gemm<0, 128><<<dim3(16 * 32), blk, 0, stream>>>(ctxb, wt_cak, bcat + 3072, nullptr, kv, 4096, 2048, 1024, 0);
    k_attn<false><<<dim3(1024), blk, 0, stream>>>(qbuf, 1024, kv, 2048, kv + 1024, 2048,
                                                  hln, 1024, 1024);
    k_gemm<2, 64><<<dim3(64 * 8), blk, 0, stream>>>(hln, wt_cao, ca_bo, x1, out, 4096, 1024, 1024, 0);

    // ---- MLP: out = x2 + W2(gelu(W1(ln2(x2)))) ----
    k_layernorm<<<dim3(4096), blk, 0, stream>>>(out, ln2_g, ln2_b, h3);
    k_gemm2<1><<<dim3(32 * 16), blk, 0, stream>>>(h3, w1t, b1, m1, 4096, 4096, 1024, 0);
    k_gemm<2, 64><<<dim3(64 * 8), blk, 0, stream>>>(m1, w2t, b2, out, out, 4096, 1024, 4096, 0);
}

// Round 18
// 322.671 us; speedup vs baseline: 1.0483x; 1.0317x over previous
//
#include <hip/hip_runtime.h>
#include <hip/hip_bf16.h>

typedef __attribute__((ext_vector_type(8))) short s8v;   // 8 x bf16 (bit pattern)
typedef __attribute__((ext_vector_type(4))) float f4v;   // MFMA accumulator

#define DEV static __device__ __forceinline__

__device__ const float SCQ = 0.18033688011112042f;   // (1/8) * log2(e)

DEV unsigned short f2bf(float f) {
    unsigned int u = __builtin_bit_cast(unsigned int, f);
    unsigned int r = u + 0x7FFFu + ((u >> 16) & 1u);
    return (unsigned short)(r >> 16);
}

DEV f4v fzero() { f4v v = {0.f, 0.f, 0.f, 0.f}; return v; }

// fast GELU (tanh form): x * sigmoid(1.5957691*(x + 0.044715 x^3))
DEV float fgelu(float x) {
    float z = x * (1.5957691f + 0.07135482f * x * x);
    float s = __builtin_amdgcn_rcpf(1.0f + __expf(-z));
    return x * s;
}

DEV void gload16(const void* g, void* l) {
    __builtin_amdgcn_global_load_lds(
        (const __attribute__((address_space(1))) unsigned int*)g,
        (__attribute__((address_space(3))) unsigned int*)l, 16, 0, 0);
}

// ================= unified prep kernel =====================================
// jobs [0,8192):      8 square (1024,1024) f32->bf16 transposes
// jobs [8192,12288):  w1 (K=1024,N=4096) transpose
// jobs [12288,16384): w2 (K=4096,N=1024) transpose
// jobs [16384,18432): ctx f32->bf16 cast (4M elements)
// jobs [18432,18452): bias concat (5120)
struct PrepArgs {
    const float* sq[8];
    const float* w1; const float* w2; const float* ctx;
    const float* b0; const float* b1; const float* b2; const float* b3; const float* b4;
    unsigned short* wt_base; unsigned short* w1t; unsigned short* w2t;
    unsigned short* ctxb; float* bcat;
};
__global__ __launch_bounds__(256) void k_prep(PrepArgs a) {
    __shared__ float tile[32][33];
    int id = blockIdx.x;
    int tid = threadIdx.x;
    if (id < 16384) {
        const float* W; unsigned short* Wt; int K, N, n0, k0;
        if (id < 8192) {
            int z = id >> 10, t = id & 1023;
            W = a.sq[z]; Wt = a.wt_base + (size_t)z * 1024 * 1024;
            K = 1024; N = 1024;
            n0 = (t & 31) * 32; k0 = (t >> 5) * 32;
        } else if (id < 12288) {
            int t = id - 8192;
            W = a.w1; Wt = a.w1t; K = 1024; N = 4096;
            n0 = (t & 127) * 32; k0 = (t >> 7) * 32;
        } else {
            int t = id - 12288;
            W = a.w2; Wt = a.w2t; K = 4096; N = 1024;
            n0 = (t & 31) * 32; k0 = (t >> 5) * 32;
        }
        int tx = tid & 31, ty = tid >> 5;
#pragma unroll
        for (int r = 0; r < 32; r += 8)
            tile[ty + r][tx] = W[(size_t)(k0 + ty + r) * N + n0 + tx];
        __syncthreads();
#pragma unroll
        for (int r = 0; r < 32; r += 8)
            Wt[(size_t)(n0 + ty + r) * K + k0 + tx] = f2bf(tile[tx][ty + r]);
    } else if (id < 18432) {
        int i = (id - 16384) * 2048 + tid * 8;
        float4 v0 = *(const float4*)(a.ctx + i);
        float4 v1 = *(const float4*)(a.ctx + i + 4);
        uint4 o;
        o.x = f2bf(v0.x) | ((unsigned)f2bf(v0.y) << 16);
        o.y = f2bf(v0.z) | ((unsigned)f2bf(v0.w) << 16);
        o.z = f2bf(v1.x) | ((unsigned)f2bf(v1.y) << 16);
        o.w = f2bf(v1.z) | ((unsigned)f2bf(v1.w) << 16);
        *(uint4*)(a.ctxb + i) = o;
    } else {
        int i = (id - 18432) * 256 + tid;   // 5120 total
        float val;
        if (i < 1024) val = a.b0[i];
        else if (i < 2048) val = a.b1[i - 1024];
        else if (i < 3072) val = a.b2[i - 2048];
        else if (i < 4096) val = a.b3[i - 3072];
        else val = a.b4[i - 4096];
        a.bcat[i] = val;
    }
}

// ---------------- LayerNorm f32 -> bf16 (C=1024) ----------------
__global__ __launch_bounds__(256) void k_layernorm(
        const float* __restrict__ x, const float* __restrict__ g,
        const float* __restrict__ b, unsigned short* __restrict__ out) {
    int row = blockIdx.x;
    int t = threadIdx.x;
    const float* xr = x + (size_t)row * 1024;
    float4 v = *(const float4*)(xr + t * 4);
    float s = v.x + v.y + v.z + v.w;
    float ss = v.x * v.x + v.y * v.y + v.z * v.z + v.w * v.w;
#pragma unroll
    for (int m = 1; m < 64; m <<= 1) { s += __shfl_xor(s, m); ss += __shfl_xor(ss, m); }
    __shared__ float red[16];
    int w = t >> 6;
    if ((t & 63) == 0) { red[w] = s; red[8 + w] = ss; }
    __syncthreads();
    s = red[0] + red[1] + red[2] + red[3];
    ss = red[8] + red[9] + red[10] + red[11];
    float mu = s * (1.f / 1024.f);
    float rstd = rsqrtf(ss * (1.f / 1024.f) - mu * mu + 1e-5f);
    float4 gv = *(const float4*)(g + t * 4);
    float4 bv = *(const float4*)(b + t * 4);
    float y0 = (v.x - mu) * rstd * gv.x + bv.x;
    float y1 = (v.y - mu) * rstd * gv.y + bv.y;
    float y2 = (v.z - mu) * rstd * gv.z + bv.z;
    float y3 = (v.w - mu) * rstd * gv.w + bv.w;
    uint2 o;
    o.x = f2bf(y0) | ((unsigned)f2bf(y1) << 16);
    o.y = f2bf(y2) | ((unsigned)f2bf(y3) << 16);
    *(uint2*)(out + (size_t)row * 1024 + t * 4) = o;
}

// ============ GEMM v1: 128/64 x 128 tile ===================================
// EPI 0: bf16+bias (cols<scaleN get x SCQ)  1: bf16 fgelu  2: f32 res+acc+bias
template <int EPI, int BM>
__global__ __launch_bounds__(256) void k_gemm(
        const unsigned short* __restrict__ A, const unsigned short* __restrict__ Bt,
        const float* __restrict__ bias, const float* __restrict__ res,
        void* __restrict__ outv, int M, int N, int K, int scaleN) {
    constexpr int WI = (BM == 128) ? 4 : 2;       // 16-row frags per wave
    constexpr int ABUF = BM * 64;                 // bytes per A buffer
    constexpr int BUFSZ = ABUF + 8192;            // A + B per K-tile
    __shared__ __align__(16) char smem[3 * BUFSZ];
    int nbx = N >> 7;
    int bid = blockIdx.x;
    int cpx = gridDim.x >> 3;          // all grids are %8 == 0
    int swz = (bid & 7) * cpx + (bid >> 3);
    int bx = swz % nbx, by = swz / nbx;
    int m0 = by * BM, n0 = bx << 7;
    int tid = threadIdx.x, w = tid >> 6, l = tid & 63;
    int wr = w >> 1, wc = w & 1;
    int lq = l >> 4, lc = l & 15;
    f4v acc[WI][4];
#pragma unroll
    for (int i = 0; i < WI; ++i)
#pragma unroll
        for (int j = 0; j < 4; ++j) acc[i][j] = fzero();
    const unsigned short* Ab = A + (size_t)m0 * K;
    const unsigned short* Bb = Bt + (size_t)n0 * K;
    int arow = w * 16 + (l >> 2);                       // 0..63
    int ach = (((l & 3) ^ ((arow >> 1) & 3)) << 3);     // pre-swizzled k-chunk

    auto STAGE = [&](int t) {
        int kt = t << 5;
        char* buf = smem + (t % 3) * BUFSZ;
        gload16(Ab + (size_t)arow * K + kt + ach, buf + w * 1024);
        if constexpr (BM == 128)
            gload16(Ab + (size_t)(64 + arow) * K + kt + ach, buf + 4096 + w * 1024);
        gload16(Bb + (size_t)arow * K + kt + ach, buf + ABUF + w * 1024);
        gload16(Bb + (size_t)(64 + arow) * K + kt + ach, buf + ABUF + 4096 + w * 1024);
    };
    int cs = ((lq ^ ((lc >> 1) & 3)) << 4);             // read-side swizzle
    auto COMPUTE = [&](int t) {
        const char* buf = smem + (t % 3) * BUFSZ;
        s8v af[WI], bfr[4];
#pragma unroll
        for (int i = 0; i < WI; ++i)
            af[i] = *(const s8v*)(buf + (wr * (BM / 2) + i * 16 + lc) * 64 + cs);
#pragma unroll
        for (int j = 0; j < 4; ++j)
            bfr[j] = *(const s8v*)(buf + ABUF + (wc * 64 + j * 16 + lc) * 64 + cs);
        __builtin_amdgcn_s_setprio(1);
#pragma unroll
        for (int i = 0; i < WI; ++i)
#pragma unroll
            for (int j = 0; j < 4; ++j)
                acc[i][j] = __builtin_amdgcn_mfma_f32_16x16x32_bf16(af[i], bfr[j], acc[i][j], 0, 0, 0);
        __builtin_amdgcn_s_setprio(0);
    };

    int NT = K >> 5;
    STAGE(0); STAGE(1);
    if constexpr (BM == 128) asm volatile("s_waitcnt vmcnt(4)" ::: "memory");
    else                     asm volatile("s_waitcnt vmcnt(3)" ::: "memory");
    __builtin_amdgcn_s_barrier();
    for (int t = 0; t < NT; ++t) {
        if (t + 2 < NT) STAGE(t + 2);
        COMPUTE(t);
        if (t + 2 < NT) {
            if constexpr (BM == 128) asm volatile("s_waitcnt vmcnt(4)" ::: "memory");
            else                     asm volatile("s_waitcnt vmcnt(3)" ::: "memory");
        } else if (t + 1 < NT) {
            asm volatile("s_waitcnt vmcnt(0)" ::: "memory");
        }
        __builtin_amdgcn_s_barrier();
    }

    // ---- epilogue: LDS bounce -> coalesced 8/16B stores ----
    float* esc = (float*)smem + w * 1088;   // per-wave 16 rows x 68 words
#pragma unroll
    for (int i = 0; i < WI; ++i) {
#pragma unroll
        for (int j = 0; j < 4; ++j)
#pragma unroll
            for (int r = 0; r < 4; ++r)
                esc[(lq * 4 + r) * 68 + j * 16 + lc] = acc[i][j][r];
#pragma unroll
        for (int p = 0; p < 4; ++p) {
            int rr = p * 4 + lq;
            float4 v = *(const float4*)(esc + rr * 68 + lc * 4);
            int row = m0 + wr * (BM / 2) + i * 16 + rr;
            int col = n0 + wc * 64 + lc * 4;
            float4 bv = *(const float4*)(bias + col);
            v.x += bv.x; v.y += bv.y; v.z += bv.z; v.w += bv.w;
            size_t idx = (size_t)row * N + col;
            if (EPI == 0) {
                float scl = (col < scaleN) ? SCQ : 1.0f;
                ushort4 o;
                o.x = f2bf(v.x * scl); o.y = f2bf(v.y * scl);
                o.z = f2bf(v.z * scl); o.w = f2bf(v.w * scl);
                *(ushort4*)((unsigned short*)outv + idx) = o;
            } else if (EPI == 1) {
                ushort4 o;
                o.x = f2bf(fgelu(v.x)); o.y = f2bf(fgelu(v.y));
                o.z = f2bf(fgelu(v.z)); o.w = f2bf(fgelu(v.w));
                *(ushort4*)((unsigned short*)outv + idx) = o;
            } else {
                float4 rv = *(const float4*)(res + idx);
                v.x += rv.x; v.y += rv.y; v.z += rv.z; v.w += rv.w;
                *(float4*)((float*)outv + idx) = v;
            }
        }
    }
}

// ============ dual GEMM: CA-Q (256 blocks) + KV (512 blocks) in one launch ==
// Both BM=128, EPI=0, K=1024. Block-uniform param select after XCD swizzle.
__global__ __launch_bounds__(256) void k_gemm_dual(
        const unsigned short* __restrict__ A0, const unsigned short* __restrict__ B0,
        const float* __restrict__ bias0, void* __restrict__ out0, int N0, int scaleN0,
        const unsigned short* __restrict__ A1, const unsigned short* __restrict__ B1,
        const float* __restrict__ bias1, void* __restrict__ out1, int N1, int scaleN1,
        int K) {
    constexpr int ABUF = 128 * 64;
    constexpr int BUFSZ = ABUF + 8192;
    __shared__ __align__(16) char smem[3 * BUFSZ];
    int bid = blockIdx.x;
    int cpx = gridDim.x >> 3;
    int swz = (bid & 7) * cpx + (bid >> 3);
    const unsigned short* A; const unsigned short* Bt; const float* bias;
    void* outv; int N, scaleN, lb;
    if (swz < 256) { A = A0; Bt = B0; bias = bias0; outv = out0; N = N0; scaleN = scaleN0; lb = swz; }
    else           { A = A1; Bt = B1; bias = bias1; outv = out1; N = N1; scaleN = scaleN1; lb = swz - 256; }
    int nbx = N >> 7;
    int bx = lb % nbx, by = lb / nbx;
    int m0 = by << 7, n0 = bx << 7;
    int tid = threadIdx.x, w = tid >> 6, l = tid & 63;
    int wr = w >> 1, wc = w & 1;
    int lq = l >> 4, lc = l & 15;
    f4v acc[4][4];
#pragma unroll
    for (int i = 0; i < 4; ++i)
#pragma unroll
        for (int j = 0; j < 4; ++j) acc[i][j] = fzero();
    const unsigned short* Ab = A + (size_t)m0 * K;
    const unsigned short* Bb = Bt + (size_t)n0 * K;
    int arow = w * 16 + (l >> 2);
    int ach = (((l & 3) ^ ((arow >> 1) & 3)) << 3);

    auto STAGE = [&](int t) {
        int kt = t << 5;
        char* buf = smem + (t % 3) * BUFSZ;
        gload16(Ab + (size_t)arow * K + kt + ach, buf + w * 1024);
        gload16(Ab + (size_t)(64 + arow) * K + kt + ach, buf + 4096 + w * 1024);
        gload16(Bb + (size_t)arow * K + kt + ach, buf + ABUF + w * 1024);
        gload16(Bb + (size_t)(64 + arow) * K + kt + ach, buf + ABUF + 4096 + w * 1024);
    };
    int cs = ((lq ^ ((lc >> 1) & 3)) << 4);
    auto COMPUTE = [&](int t) {
        const char* buf = smem + (t % 3) * BUFSZ;
        s8v af[4], bfr[4];
#pragma unroll
        for (int i = 0; i < 4; ++i)
            af[i] = *(const s8v*)(buf + (wr * 64 + i * 16 + lc) * 64 + cs);
#pragma unroll
        for (int j = 0; j < 4; ++j)
            bfr[j] = *(const s8v*)(buf + ABUF + (wc * 64 + j * 16 + lc) * 64 + cs);
        __builtin_amdgcn_s_setprio(1);
#pragma unroll
        for (int i = 0; i < 4; ++i)
#pragma unroll
            for (int j = 0; j < 4; ++j)
                acc[i][j] = __builtin_amdgcn_mfma_f32_16x16x32_bf16(af[i], bfr[j], acc[i][j], 0, 0, 0);
        __builtin_amdgcn_s_setprio(0);
    };

    int NT = K >> 5;
    STAGE(0); STAGE(1);
    asm volatile("s_waitcnt vmcnt(4)" ::: "memory");
    __builtin_amdgcn_s_barrier();
    for (int t = 0; t < NT; ++t) {
        if (t + 2 < NT) STAGE(t + 2);
        COMPUTE(t);
        if (t + 2 < NT) {
            asm volatile("s_waitcnt vmcnt(4)" ::: "memory");
        } else if (t + 1 < NT) {
            asm volatile("s_waitcnt vmcnt(0)" ::: "memory");
        }
        __builtin_amdgcn_s_barrier();
    }

    float* esc = (float*)smem + w * 1088;
#pragma unroll
    for (int i = 0; i < 4; ++i) {
#pragma unroll
        for (int j = 0; j < 4; ++j)
#pragma unroll
            for (int r = 0; r < 4; ++r)
                esc[(lq * 4 + r) * 68 + j * 16 + lc] = acc[i][j][r];
#pragma unroll
        for (int p = 0; p < 4; ++p) {
            int rr = p * 4 + lq;
            float4 v = *(const float4*)(esc + rr * 68 + lc * 4);
            int row = m0 + wr * 64 + i * 16 + rr;
            int col = n0 + wc * 64 + lc * 4;
            float4 bv = *(const float4*)(bias + col);
            v.x += bv.x; v.y += bv.y; v.z += bv.z; v.w += bv.w;
            size_t idx = (size_t)row * N + col;
            float scl = (col < scaleN) ? SCQ : 1.0f;
            ushort4 o;
            o.x = f2bf(v.x * scl); o.y = f2bf(v.y * scl);
            o.z = f2bf(v.z * scl); o.w = f2bf(v.w * scl);
            *(ushort4*)((unsigned short*)outv + idx) = o;
        }
    }
}

// ============ GEMM v2: 128x256 tile, wave = 64x128 (acc 4x8) ===============
// EPI 0: bf16+bias (cols<scaleN get x SCQ)   1: bf16 fgelu
template <int EPI>
__global__ __launch_bounds__(256, 2) void k_gemm2(
        const unsigned short* __restrict__ A, const unsigned short* __restrict__ Bt,
        const float* __restrict__ bias, void* __restrict__ outv,
        int M, int N, int K, int scaleN) {
    constexpr int BUFSZ = 8192 + 16384;   // A(128x64B) + B(256x64B)
    __shared__ __align__(16) char smem[3 * BUFSZ];
    int nbx = N >> 8;
    int bid = blockIdx.x;
    int cpx = gridDim.x >> 3;             // grids are %8 == 0
    int swz = (bid & 7) * cpx + (bid >> 3);
    int bx = swz % nbx, by = swz / nbx;
    int m0 = by << 7, n0 = bx << 8;
    int tid = threadIdx.x, w = tid >> 6, l = tid & 63;
    int wr = w >> 1, wc = w & 1;
    int lq = l >> 4, lc = l & 15;
    f4v acc[4][8];
#pragma unroll
    for (int i = 0; i < 4; ++i)
#pragma unroll
        for (int j = 0; j < 8; ++j) acc[i][j] = fzero();
    const unsigned short* Ab = A + (size_t)m0 * K;
    const unsigned short* Bb = Bt + (size_t)n0 * K;
    int arow = w * 16 + (l >> 2);                       // 0..63
    int ach = (((l & 3) ^ ((arow >> 1) & 3)) << 3);     // pre-swizzled k-chunk

    auto STAGE_P0 = [&](int t) {       // A both halves + B halves 0,1
        int kt = t << 5;
        char* buf = smem + (t % 3) * BUFSZ;
        gload16(Ab + (size_t)arow * K + kt + ach, buf + w * 1024);
        gload16(Ab + (size_t)(64 + arow) * K + kt + ach, buf + 4096 + w * 1024);
        gload16(Bb + (size_t)arow * K + kt + ach, buf + 8192 + w * 1024);
        gload16(Bb + (size_t)(64 + arow) * K + kt + ach, buf + 8192 + 4096 + w * 1024);
    };
    auto STAGE_P1 = [&](int t) {       // B halves 2,3
        int kt = t << 5;
        char* buf = smem + (t % 3) * BUFSZ;
        gload16(Bb + (size_t)(128 + arow) * K + kt + ach, buf + 8192 + 8192 + w * 1024);
        gload16(Bb + (size_t)(192 + arow) * K + kt + ach, buf + 8192 + 12288 + w * 1024);
    };
    int cs = ((lq ^ ((lc >> 1) & 3)) << 4);             // read-side swizzle

    int NT = K >> 5;
    STAGE_P0(0); STAGE_P1(0); STAGE_P0(1); STAGE_P1(1);
    asm volatile("s_waitcnt vmcnt(6)" ::: "memory");
    __builtin_amdgcn_s_barrier();
    for (int t = 0; t < NT; ++t) {
        const char* buf = smem + (t % 3) * BUFSZ;
        bool pf = (t + 2 < NT);
        // ---- phase A: A frags + B cols 0..3; stage 4 of 6 ----
        s8v af[4], bfr[8];
#pragma unroll
        for (int i = 0; i < 4; ++i)
            af[i] = *(const s8v*)(buf + (wr * 64 + i * 16 + lc) * 64 + cs);
#pragma unroll
        for (int j = 0; j < 4; ++j)
            bfr[j] = *(const s8v*)(buf + 8192 + (wc * 128 + j * 16 + lc) * 64 + cs);
        if (pf) STAGE_P0(t + 2);
        asm volatile("s_waitcnt lgkmcnt(0)" ::: "memory");
        __builtin_amdgcn_sched_barrier(0);
        __builtin_amdgcn_s_setprio(1);
#pragma unroll
        for (int i = 0; i < 4; ++i)
#pragma unroll
            for (int j = 0; j < 4; ++j)
                acc[i][j] = __builtin_amdgcn_mfma_f32_16x16x32_bf16(af[i], bfr[j], acc[i][j], 0, 0, 0);
        __builtin_amdgcn_s_setprio(0);
        // ---- phase B: B cols 4..7; stage remaining 2 ----
#pragma unroll
        for (int j = 4; j < 8; ++j)
            bfr[j] = *(const s8v*)(buf + 8192 + (wc * 128 + j * 16 + lc) * 64 + cs);
        if (pf) STAGE_P1(t + 2);
        asm volatile("s_waitcnt lgkmcnt(0)" ::: "memory");
        __builtin_amdgcn_sched_barrier(0);
        __builtin_amdgcn_s_setprio(1);
#pragma unroll
        for (int i = 0; i < 4; ++i)
#pragma unroll
            for (int j = 4; j < 8; ++j)
                acc[i][j] = __builtin_amdgcn_mfma_f32_16x16x32_bf16(af[i], bfr[j], acc[i][j], 0, 0, 0);
        __builtin_amdgcn_s_setprio(0);
        if (pf) {
            asm volatile("s_waitcnt vmcnt(6)" ::: "memory");
        } else if (t + 1 < NT) {
            asm volatile("s_waitcnt vmcnt(0)" ::: "memory");
        }
        __builtin_amdgcn_s_barrier();
    }

    // ---- epilogue: LDS bounce -> coalesced stores (wave: 64 x 128) ----
    float* esc = (float*)smem + w * 2112;   // per-wave 16 rows x 132 words
#pragma unroll
    for (int i = 0; i < 4; ++i) {
#pragma unroll
        for (int j = 0; j < 8; ++j)
#pragma unroll
            for (int r = 0; r < 4; ++r)
                esc[(lq * 4 + r) * 132 + j * 16 + lc] = acc[i][j][r];
#pragma unroll
        for (int p = 0; p < 4; ++p) {
            int rr = p * 4 + lq;
            int row = m0 + wr * 64 + i * 16 + rr;
#pragma unroll
            for (int h = 0; h < 2; ++h) {
                float4 v = *(const float4*)(esc + rr * 132 + h * 64 + lc * 4);
                int col = n0 + wc * 128 + h * 64 + lc * 4;
                float4 bv = *(const float4*)(bias + col);
                v.x += bv.x; v.y += bv.y; v.z += bv.z; v.w += bv.w;
                size_t idx = (size_t)row * N + col;
                ushort4 o;
                if (EPI == 0) {
                    float scl = (col < scaleN) ? SCQ : 1.0f;
                    o.x = f2bf(v.x * scl); o.y = f2bf(v.y * scl);
                    o.z = f2bf(v.z * scl); o.w = f2bf(v.w * scl);
                } else {
                    o.x = f2bf(fgelu(v.x)); o.y = f2bf(fgelu(v.y));
                    o.z = f2bf(fgelu(v.z)); o.w = f2bf(fgelu(v.w));
                }
                *(ushort4*)((unsigned short*)outv + idx) = o;
            }
        }
    }
}

// ---------------- fused flash attention (d=64, 64x64 tiles, 4 waves) ----------
// Swapped QK^T (Q pre-scaled by SCQ); defer-max (THR=8); P->bf16 via
// v_cvt_pk_bf16_f32; double-buffered K/V async-stage split; XCD swizzle.
// CAUSAL: mirrored q-tile pairing {pr, nqt-1-pr} (balanced 17 tile-rounds).
template <bool CAUSAL>
__global__ __launch_bounds__(256) void k_attn(
        const unsigned short* __restrict__ Q, int ldq,
        const unsigned short* __restrict__ Kp, int ldk,
        const unsigned short* __restrict__ Vp, int ldv,
        unsigned short* __restrict__ O, int ldo, int T) {
    __shared__ unsigned short Ks[2][64 * 64];  // [t][d], chunk-swizzled
    __shared__ unsigned short Vt[2][64 * 64];  // [d][t], chunk-swizzled
    __shared__ unsigned short Ps[4][16 * 64];  // per-wave P [q16][k64], swizzled
    int nqt = T >> 6;
    int bid = blockIdx.x;
    int cpx = gridDim.x >> 3;
    int swzb = (bid & 7) * cpx + (bid >> 3);
    int qt0, qt1, bh;
    if (CAUSAL) {
        int pairs = nqt >> 1;
        int pr = swzb % pairs;
        bh = swzb / pairs;
        qt0 = pr; qt1 = nqt - 1 - pr;
    } else {
        qt1 = swzb % nqt;
        bh = swzb / nqt;
        qt0 = 0;
    }
    int b = bh >> 4, h = bh & 15;
    int tid = threadIdx.x, w = tid >> 6, l = tid & 63;
    int lq = l >> 4, lc = l & 15;
    size_t qoff = (size_t)b * T * ldq + h * 64;
    size_t koff = (size_t)b * T * ldk + h * 64;
    size_t voff = (size_t)b * T * ldv + h * 64;
    s8v qf1[2], qf0[2];
    {
        const unsigned short* qp = Q + qoff + (size_t)(qt1 * 64 + w * 16 + lc) * ldq + lq * 8;
        qf1[0] = *(const s8v*)qp;
        qf1[1] = *(const s8v*)(qp + 32);
        if (CAUSAL) {
            const unsigned short* q0p = Q + qoff + (size_t)(qt0 * 64 + w * 16 + lc) * ldq + lq * 8;
            qf0[0] = *(const s8v*)q0p;
            qf0[1] = *(const s8v*)(q0p + 32);
        }
    }
    s8v ones;
#pragma unroll
    for (int i = 0; i < 8; ++i) ones[i] = (short)0x3F80;   // bf16 1.0
    f4v o1[4], o0[4];
    float l1r[4], l0r[4];
    float m1 = -3.0e38f, m0 = -3.0e38f;
#pragma unroll
    for (int j = 0; j < 4; ++j) {
        o1[j] = fzero(); o0[j] = fzero(); l1r[j] = 0.f; l0r[j] = 0.f;
    }
    int p = tid & 31, dbase = (tid >> 5) * 8;
    s8v v0r, v1r;   // V staging registers

    auto STAGE_K = [&](int kt, int bufi) {
#pragma unroll
        for (int s = 0; s < 2; ++s) {
            int idx = s * 256 + w * 64 + l;
            int t = idx >> 3;
            int ch = (idx & 7) ^ (t & 7);
            gload16(Kp + koff + (size_t)(kt * 64 + t) * ldk + ch * 8,
                    (char*)Ks[bufi] + s * 4096 + w * 1024);
        }
    };
    auto LOAD_V = [&](int kt) {
        const unsigned short* vp = Vp + voff + (size_t)(kt * 64 + 2 * p) * ldv + dbase;
        v0r = *(const s8v*)vp;
        v1r = *(const s8v*)(vp + ldv);
    };
    auto WRITE_V = [&](int bufi) {
#pragma unroll
        for (int j = 0; j < 8; ++j) {
            int dd = dbase + j;
            unsigned int val = (unsigned short)v0r[j] | ((unsigned)(unsigned short)v1r[j] << 16);
            *(unsigned int*)((char*)Vt[bufi] + dd * 128 +
                             ((((p >> 2) ^ (dd & 7)) << 4) | ((p & 3) << 2))) = val;
        }
    };

    auto SMPV = [&](f4v (&sa)[4], f4v (&oa)[4], float& mr, float (&lr)[4],
                    int bufi, int qt, int kt) {
        bool diag = CAUSAL && (kt == qt);
        int qloc = w * 16 + lc;
        float pv[16];
#pragma unroll
        for (int jn = 0; jn < 4; ++jn)
#pragma unroll
            for (int j = 0; j < 4; ++j) {
                float sv = sa[jn][j];   // S already scaled (Q pre-scaled)
                if (diag && (jn * 16 + lq * 4 + j > qloc)) sv = -3.0e38f;
                pv[jn * 4 + j] = sv;
            }
        float t8[8];
#pragma unroll
        for (int i = 0; i < 8; ++i) t8[i] = fmaxf(pv[2 * i], pv[2 * i + 1]);
        float t4a = fmaxf(t8[0], t8[1]), t4b = fmaxf(t8[2], t8[3]);
        float t4c = fmaxf(t8[4], t8[5]), t4d = fmaxf(t8[6], t8[7]);
        float tm = fmaxf(fmaxf(t4a, t4b), fmaxf(t4c, t4d));
        tm = fmaxf(tm, __shfl_xor(tm, 16));
        tm = fmaxf(tm, __shfl_xor(tm, 32));
        if (!__all(tm <= mr + 8.0f)) {
            float mnew = fmaxf(mr, tm);
            float alpha = exp2f(mr - mnew);
            mr = mnew;
#pragma unroll
            for (int j = 0; j < 4; ++j) {
                float aj = __shfl(alpha, lq * 4 + j);
                lr[j] *= aj;
#pragma unroll
                for (int jn = 0; jn < 4; ++jn) oa[jn][j] *= aj;
            }
        }
#pragma unroll
        for (int jn = 0; jn < 4; ++jn) {
            float e0 = exp2f(pv[jn * 4 + 0] - mr);
            float e1 = exp2f(pv[jn * 4 + 1] - mr);
            float e2 = exp2f(pv[jn * 4 + 2] - mr);
            float e3 = exp2f(pv[jn * 4 + 3] - mr);
            unsigned r0, r1;
            asm("v_cvt_pk_bf16_f32 %0, %1, %2" : "=v"(r0) : "v"(e0), "v"(e1));
            asm("v_cvt_pk_bf16_f32 %0, %1, %2" : "=v"(r1) : "v"(e2), "v"(e3));
            int chunk = (jn * 2 + (lq >> 1)) ^ (lc & 7);
            char* basep = (char*)Ps[w] + lc * 128 + (chunk << 4) + ((lq & 1) << 3);
            uint2 rr; rr.x = r0; rr.y = r1;
            *(uint2*)basep = rr;
        }
        s8v pa[2];
#pragma unroll
        for (int kc = 0; kc < 2; ++kc)
            pa[kc] = *(const s8v*)((const char*)Ps[w] + lc * 128 +
                                   (((kc * 4 + lq) ^ (lc & 7)) << 4));
        f4v sone = fzero();
        __builtin_amdgcn_s_setprio(1);
#pragma unroll
        for (int kc = 0; kc < 2; ++kc) {
            sone = __builtin_amdgcn_mfma_f32_16x16x32_bf16(pa[kc], ones, sone, 0, 0, 0);
#pragma unroll
            for (int jn = 0; jn < 4; ++jn) {
                int dd = jn * 16 + lc;
                s8v bf = *(const s8v*)((const char*)Vt[bufi] + dd * 128 +
                                       (((kc * 4 + lq) ^ (dd & 7)) << 4));
                oa[jn] = __builtin_amdgcn_mfma_f32_16x16x32_bf16(pa[kc], bf, oa[jn], 0, 0, 0);
            }
        }
        __builtin_amdgcn_s_setprio(0);
#pragma unroll
        for (int j = 0; j < 4; ++j) lr[j] += sone[j];
    };

    int ktend = CAUSAL ? (qt1 + 1) : nqt;
    STAGE_K(0, 0); LOAD_V(0);
    asm volatile("s_waitcnt vmcnt(0)" ::: "memory");
    WRITE_V(0);
    __syncthreads();
    int buf = 0;
    for (int kt = 0; kt < ktend; ++kt) {
        bool pf = (kt + 1 < ktend);
        if (pf) { STAGE_K(kt + 1, buf ^ 1); LOAD_V(kt + 1); }
        bool do0 = CAUSAL && (kt <= qt0);
        f4v sa1[4], sa0[4];
        __builtin_amdgcn_s_setprio(1);
#pragma unroll
        for (int jn = 0; jn < 4; ++jn) {
            sa1[jn] = fzero(); sa0[jn] = fzero();
            int t = jn * 16 + lc;
#pragma unroll
            for (int kc = 0; kc < 2; ++kc) {
                s8v kf = *(const s8v*)((const char*)Ks[buf] + t * 128 +
                                       (((kc * 4 + lq) ^ (t & 7)) << 4));
                sa1[jn] = __builtin_amdgcn_mfma_f32_16x16x32_bf16(kf, qf1[kc], sa1[jn], 0, 0, 0);
                if (do0)
                    sa0[jn] = __builtin_amdgcn_mfma_f32_16x16x32_bf16(kf, qf0[kc], sa0[jn], 0, 0, 0);
            }
        }
        __builtin_amdgcn_s_setprio(0);
        SMPV(sa1, o1, m1, l1r, buf, qt1, kt);
        if (do0) SMPV(sa0, o0, m0, l0r, buf, qt0, kt);
        if (pf) {
            asm volatile("s_waitcnt vmcnt(0)" ::: "memory");
            WRITE_V(buf ^ 1);
        }
        __syncthreads();
        buf ^= 1;
    }
#pragma unroll
    for (int j = 0; j < 4; ++j) {
        float inv = 1.0f / l1r[j];
        int row = qt1 * 64 + w * 16 + lq * 4 + j;
#pragma unroll
        for (int jn = 0; jn < 4; ++jn)
            O[(size_t)(b * T + row) * ldo + h * 64 + jn * 16 + lc] = f2bf(o1[jn][j] * inv);
    }
    if (CAUSAL) {
#pragma unroll
        for (int j = 0; j < 4; ++j) {
            float inv = 1.0f / l0r[j];
            int row = qt0 * 64 + w * 16 + lq * 4 + j;
#pragma unroll
            for (int jn = 0; jn < 4; ++jn)
                O[(size_t)(b * T + row) * ldo + h * 64 + jn * 16 + lc] = f2bf(o0[jn][j] * inv);
        }
    }
}

// ---------------- orchestration ----------------
extern "C" void kernel_launch(void* const* d_in, const int* in_sizes, int n_in,
                              void* d_out, int out_size, void* d_ws, size_t ws_size,
                              hipStream_t stream) {
    const float* x     = (const float*)d_in[0];
    const float* ctx   = (const float*)d_in[1];
    const float* ln1_g = (const float*)d_in[2];
    const float* ln1_b = (const float*)d_in[3];
    const float* ln2_g = (const float*)d_in[4];
    const float* ln2_b = (const float*)d_in[5];
    const float* sa_wq = (const float*)d_in[6];  const float* sa_bq = (const float*)d_in[7];
    const float* sa_wk = (const float*)d_in[8];  const float* sa_bk = (const float*)d_in[9];
    const float* sa_wv = (const float*)d_in[10]; const float* sa_bv = (const float*)d_in[11];
    const float* sa_wo = (const float*)d_in[12]; const float* sa_bo = (const float*)d_in[13];
    const float* ca_wq = (const float*)d_in[14]; const float* ca_bq = (const float*)d_in[15];
    const float* ca_wk = (const float*)d_in[16]; const float* ca_bk = (const float*)d_in[17];
    const float* ca_wv = (const float*)d_in[18]; const float* ca_bv = (const float*)d_in[19];
    const float* ca_wo = (const float*)d_in[20]; const float* ca_bo = (const float*)d_in[21];
    const float* w1 = (const float*)d_in[22]; const float* b1 = (const float*)d_in[23];
    const float* w2 = (const float*)d_in[24]; const float* b2 = (const float*)d_in[25];
    float* out = (float*)d_out;

    char* ws = (char*)d_ws;
    const size_t MB = 1024 * 1024;
    unsigned short* wt_base = (unsigned short*)(ws + 0 * MB);  // 8 x 2MB, order below
    unsigned short* wt_saq = wt_base + 0 * 1024 * 1024;
    unsigned short* wt_cak = wt_base + 5 * 1024 * 1024;        // cak,cav contiguous
    unsigned short* wt_sao = wt_base + 3 * 1024 * 1024;
    unsigned short* wt_caq = wt_base + 4 * 1024 * 1024;
    unsigned short* wt_cao = wt_base + 7 * 1024 * 1024;
    unsigned short* w1t    = (unsigned short*)(ws + 16 * MB);  // 8MB (4096,1024)
    unsigned short* w2t    = (unsigned short*)(ws + 24 * MB);  // 8MB (1024,4096)
    unsigned short* ctxb   = (unsigned short*)(ws + 32 * MB);  // 8MB; reused as h3 in MLP
    float*          x1     = (float*)        (ws + 40 * MB);   // 16MB
    unsigned short* qbuf   = (unsigned short*)(ws + 56 * MB);  // 8MB, start of qkv region
    unsigned short* kbuf   = (unsigned short*)(ws + 64 * MB);  // 8MB, kv region
    unsigned short* hln    = (unsigned short*)(ws + 80 * MB);  // 8MB (ln out / attn out)
    float*          bcat   = (float*)        (ws + 88 * MB);   // 20KB
    unsigned short* qkv = qbuf;   // (4096,3072) spans 56..80MB
    unsigned short* kv  = kbuf;   // (4096,2048) spans 64..80MB
    unsigned short* m1  = qbuf;   // (4096,4096) = 32MB spans 56..88MB
    unsigned short* h3  = ctxb;

    dim3 blk(256);
    // ---- unified prep: 10 transposes + ctx cast + bias concat ----
    PrepArgs pa;
    pa.sq[0] = sa_wq; pa.sq[1] = sa_wk; pa.sq[2] = sa_wv; pa.sq[3] = sa_wo;
    pa.sq[4] = ca_wq; pa.sq[5] = ca_wk; pa.sq[6] = ca_wv; pa.sq[7] = ca_wo;
    pa.w1 = w1; pa.w2 = w2; pa.ctx = ctx;
    pa.b0 = sa_bq; pa.b1 = sa_bk; pa.b2 = sa_bv; pa.b3 = ca_bk; pa.b4 = ca_bv;
    pa.wt_base = wt_base; pa.w1t = w1t; pa.w2t = w2t; pa.ctxb = ctxb; pa.bcat = bcat;
    k_prep<<<dim3(18452), blk, 0, stream>>>(pa);

    // ---- self attention: x1 = x + Wo(attn(ln1(x))) ----
    k_layernorm<<<dim3(4096), blk, 0, stream>>>(x, ln1_g, ln1_b, hln);
    k_gemm<0, 128><<<dim3(768), blk, 0, stream>>>(hln, wt_saq, bcat, nullptr, qkv, 4096, 3072, 1024, 1024);
    k_attn<true><<<dim3(512), blk, 0, stream>>>(qkv, 3072, qkv + 1024, 3072, qkv + 2048, 3072,
                                                hln, 1024, 1024);
    k_gemm<2, 64><<<dim3(64 * 8), blk, 0, stream>>>(hln, wt_sao, sa_bo, x, x1, 4096, 1024, 1024, 0);

    // ---- cross attention: x2 = x1 + Wo(attn(ln2(x1), ctx)) ----
    k_layernorm<<<dim3(4096), blk, 0, stream>>>(x1, ln2_g, ln2_b, hln);
    k_gemm_dual<<<dim3(768), blk, 0, stream>>>(
        hln, wt_caq, ca_bq, qbuf, 1024, 1024,
        ctxb, wt_cak, bcat + 3072, kv, 2048, 0, 1024);
    k_attn<false><<<dim3(1024), blk, 0, stream>>>(qbuf, 1024, kv, 2048, kv + 1024, 2048,
                                                  hln, 1024, 1024);
    k_gemm<2, 64><<<dim3(64 * 8), blk, 0, stream>>>(hln, wt_cao, ca_bo, x1, out, 4096, 1024, 1024, 0);

    // ---- MLP: out = x2 + W2(gelu(W1(ln2(x2)))) ----
    k_layernorm<<<dim3(4096), blk, 0, stream>>>(out, ln2_g, ln2_b, h3);
    k_gemm2<1><<<dim3(32 * 16), blk, 0, stream>>>(h3, w1t, b1, m1, 4096, 4096, 1024, 0);
    k_gemm<2, 64><<<dim3(64 * 8), blk, 0, stream>>>(m1, w2t, b2, out, out, 4096, 1024, 4096, 0);
}